// Round 7
// baseline (2109.553 us; speedup 1.0000x reference)
//
#include <hip/hip_runtime.h>
#include <hip/hip_bf16.h>
#include <math.h>

// PointNet++ SAModule: FPS -> ball query -> PointNetConv(MLP, max-agg)
// B=16, N=4096, S=1024, K=64, r=0.1, MLP 67->64->64->128.
// Selection decisions (FPS argmax, ball membership, top-K) bit-exact vs numpy.
// R7: FPS = 2 independent clouds interleaved per block (8 blocks): two
// dependency chains fill each other's stalls. R5's proven key-only DPP ladder;
// wave-winner lane self-identifies and writes key+xyz pre-barrier; positions
// live in registers only (no pos LDS). conv/ball untouched this round.

#define NB 16
#define NP 4096
#define FIN 64
#define NS 1024
#define KN 64
#define CAP 256

__device__ __forceinline__ float dist2e(float ax, float ay, float az,
                                        float bx, float by, float bz) {
    float dx = __fsub_rn(ax, bx);
    float dy = __fsub_rn(ay, by);
    float dz = __fsub_rn(az, bz);
    return __fadd_rn(__fadd_rn(__fmul_rn(dx, dx), __fmul_rn(dy, dy)),
                     __fmul_rn(dz, dz));
}

// One DPP row-rotate reduce level on a packed u64 key (max). CTRL literal:
// 0x121=ror:1 0x122=ror:2 0x124=ror:4 0x128=ror:8. (R5-proven, bit-exact.)
#define DPP_KEY_MAX(k, CTRL)                                                   \
    do {                                                                       \
        int _lo = (int)(unsigned)((k) & 0xFFFFFFFFull);                        \
        int _hi = (int)(unsigned)((k) >> 32);                                  \
        int _plo = __builtin_amdgcn_update_dpp(_lo, _lo, CTRL, 0xF, 0xF, false);\
        int _phi = __builtin_amdgcn_update_dpp(_hi, _hi, CTRL, 0xF, 0xF, false);\
        unsigned long long _nk =                                               \
            ((unsigned long long)(unsigned)_phi << 32) | (unsigned)_plo;       \
        if (_nk > (k)) (k) = _nk;                                              \
    } while (0)

// Full wave reduce (max) of packed u64 key: 4 DPP row levels + xor16 + xor32.
#define WAVE_KEY_MAX(k)                                                        \
    do {                                                                       \
        DPP_KEY_MAX(k, 0x121);                                                 \
        DPP_KEY_MAX(k, 0x122);                                                 \
        DPP_KEY_MAX(k, 0x124);                                                 \
        DPP_KEY_MAX(k, 0x128);                                                 \
        {                                                                      \
            int _lo = (int)(unsigned)((k) & 0xFFFFFFFFull);                    \
            int _hi = (int)(unsigned)((k) >> 32);                              \
            int _plo = __builtin_amdgcn_ds_swizzle(_lo, 0x401F);               \
            int _phi = __builtin_amdgcn_ds_swizzle(_hi, 0x401F);               \
            unsigned long long _nk =                                           \
                ((unsigned long long)(unsigned)_phi << 32) | (unsigned)_plo;   \
            if (_nk > (k)) (k) = _nk;                                          \
        }                                                                      \
        {                                                                      \
            unsigned long long _nk = __shfl_xor((k), 32, 64);                  \
            if (_nk > (k)) (k) = _nk;                                          \
        }                                                                      \
    } while (0)

// -------- FPS: 8 blocks, 2 clouds/block interleaved, 16 pts/thread/cloud ----
__global__ __launch_bounds__(256, 1) void fps_kernel(
        const float* __restrict__ pos, int* __restrict__ fps_idx,
        float* __restrict__ out_pos, float* __restrict__ out_batch) {
    const int blk = blockIdx.x;            // 0..7
    const int cA = blk * 2, cB = blk * 2 + 1;
    const int tid = threadIdx.x;
    const int lane = tid & 63;
    const int wv = tid >> 6;
    __shared__ __align__(16) float bc[2][2][4][8];  // [buf][cloud][wave][slot]
    const float* pA = pos + (size_t)cA * NP * 3;
    const float* pB = pos + (size_t)cB * NP * 3;
    float Ax[16], Ay[16], Az[16], Am[16];
    float Bx[16], By[16], Bz[16], Bm[16];
#pragma unroll
    for (int i = 0; i < 16; ++i) {
        int j = tid + (i << 8);
        Ax[i] = pA[j * 3 + 0]; Ay[i] = pA[j * 3 + 1]; Az[i] = pA[j * 3 + 2];
        Bx[i] = pB[j * 3 + 0]; By[i] = pB[j * 3 + 1]; Bz[i] = pB[j * 3 + 2];
        Am[i] = INFINITY; Bm[i] = INFINITY;
    }
    float cxA = pA[0], cyA = pA[1], czA = pA[2];
    float cxB = pB[0], cyB = pB[1], czB = pB[2];
    if (tid == 0) {
        fps_idx[cA * NS] = 0;
        out_pos[(size_t)(cA * NS) * 3 + 0] = cxA;
        out_pos[(size_t)(cA * NS) * 3 + 1] = cyA;
        out_pos[(size_t)(cA * NS) * 3 + 2] = czA;
        fps_idx[cB * NS] = 0;
        out_pos[(size_t)(cB * NS) * 3 + 0] = cxB;
        out_pos[(size_t)(cB * NS) * 3 + 1] = cyB;
        out_pos[(size_t)(cB * NS) * 3 + 2] = czB;
    }
    for (int s = 1; s < NS; ++s) {
        // ---- cloud A: local md update + per-lane argmax (strict >, asc i =>
        // lowest index on tie, matching np.argmax first-occurrence)
        float bvA = -1.0f; int biA = 0;
        float wxA = 0.f, wyA = 0.f, wzA = 0.f;
#pragma unroll
        for (int i = 0; i < 16; ++i) {
            float d = dist2e(Ax[i], Ay[i], Az[i], cxA, cyA, czA);
            float m = Am[i];
            m = d < m ? d : m;   // jnp.minimum (exact)
            Am[i] = m;
            bool take = (m > bvA);
            bvA = take ? m : bvA;
            biA = take ? (tid + (i << 8)) : biA;
            wxA = take ? Ax[i] : wxA;
            wyA = take ? Ay[i] : wyA;
            wzA = take ? Az[i] : wzA;
        }
        unsigned long long keyA =
            ((unsigned long long)__float_as_uint(bvA) << 32) |
            (unsigned)(~(unsigned)biA);
        const unsigned long long myA = keyA;
        // ---- cloud B: local
        float bvB = -1.0f; int biB = 0;
        float wxB = 0.f, wyB = 0.f, wzB = 0.f;
#pragma unroll
        for (int i = 0; i < 16; ++i) {
            float d = dist2e(Bx[i], By[i], Bz[i], cxB, cyB, czB);
            float m = Bm[i];
            m = d < m ? d : m;
            Bm[i] = m;
            bool take = (m > bvB);
            bvB = take ? m : bvB;
            biB = take ? (tid + (i << 8)) : biB;
            wxB = take ? Bx[i] : wxB;
            wyB = take ? By[i] : wyB;
            wzB = take ? Bz[i] : wzB;
        }
        unsigned long long keyB =
            ((unsigned long long)__float_as_uint(bvB) << 32) |
            (unsigned)(~(unsigned)biB);
        const unsigned long long myB = keyB;
        // ---- wave reductions (independent chains -> scheduler interleaves)
        WAVE_KEY_MAX(keyA);
        WAVE_KEY_MAX(keyB);
        const int buf = s & 1;  // double buffer -> one barrier per step
        if (myA == keyA) {      // unique winner lane per wave (idx in key)
            bc[buf][0][wv][0] = __uint_as_float((unsigned)(keyA & 0xFFFFFFFFull));
            bc[buf][0][wv][1] = __uint_as_float((unsigned)(keyA >> 32));
            bc[buf][0][wv][2] = wxA;
            bc[buf][0][wv][3] = wyA;
            bc[buf][0][wv][4] = wzA;
        }
        if (myB == keyB) {
            bc[buf][1][wv][0] = __uint_as_float((unsigned)(keyB & 0xFFFFFFFFull));
            bc[buf][1][wv][1] = __uint_as_float((unsigned)(keyB >> 32));
            bc[buf][1][wv][2] = wxB;
            bc[buf][1][wv][3] = wyB;
            bc[buf][1][wv][4] = wzB;
        }
        __syncthreads();
        // ---- select best of 4 wave candidates, cloud A
        unsigned long long bkA; float nxA, nyA, nzA;
        {
            float4 e = *(const float4*)&bc[buf][0][0][0];
            bkA = ((unsigned long long)__float_as_uint(e.y) << 32) |
                  __float_as_uint(e.x);
            nxA = e.z; nyA = e.w; nzA = bc[buf][0][0][4];
        }
#pragma unroll
        for (int w = 1; w < 4; ++w) {
            float4 e = *(const float4*)&bc[buf][0][w][0];
            unsigned long long k2 =
                ((unsigned long long)__float_as_uint(e.y) << 32) |
                __float_as_uint(e.x);
            float z2 = bc[buf][0][w][4];
            bool take = (k2 > bkA);
            bkA = take ? k2 : bkA;
            nxA = take ? e.z : nxA;
            nyA = take ? e.w : nyA;
            nzA = take ? z2 : nzA;
        }
        // ---- select, cloud B
        unsigned long long bkB; float nxB, nyB, nzB;
        {
            float4 e = *(const float4*)&bc[buf][1][0][0];
            bkB = ((unsigned long long)__float_as_uint(e.y) << 32) |
                  __float_as_uint(e.x);
            nxB = e.z; nyB = e.w; nzB = bc[buf][1][0][4];
        }
#pragma unroll
        for (int w = 1; w < 4; ++w) {
            float4 e = *(const float4*)&bc[buf][1][w][0];
            unsigned long long k2 =
                ((unsigned long long)__float_as_uint(e.y) << 32) |
                __float_as_uint(e.x);
            float z2 = bc[buf][1][w][4];
            bool take = (k2 > bkB);
            bkB = take ? k2 : bkB;
            nxB = take ? e.z : nxB;
            nyB = take ? e.w : nyB;
            nzB = take ? z2 : nzB;
        }
        const int curA = (int)(~(unsigned)(bkA & 0xFFFFFFFFull));
        const int curB = (int)(~(unsigned)(bkB & 0xFFFFFFFFull));
        cxA = nxA; cyA = nyA; czA = nzA;
        cxB = nxB; cyB = nyB; czB = nzB;
        if (tid == 0) {
            fps_idx[cA * NS + s] = curA;
            out_pos[(size_t)(cA * NS + s) * 3 + 0] = nxA;
            out_pos[(size_t)(cA * NS + s) * 3 + 1] = nyA;
            out_pos[(size_t)(cA * NS + s) * 3 + 2] = nzA;
            fps_idx[cB * NS + s] = curB;
            out_pos[(size_t)(cB * NS + s) * 3 + 0] = nxB;
            out_pos[(size_t)(cB * NS + s) * 3 + 1] = nyB;
            out_pos[(size_t)(cB * NS + s) * 3 + 2] = nzB;
        }
    }
    for (int s = tid; s < NS; s += 256) {
        out_batch[cA * NS + s] = (float)cA;
        out_batch[cB * NS + s] = (float)cB;
    }
}

// ------------- ball query: 16 blocks/cloud, 64 centers/block, wave/center ----
__global__ __launch_bounds__(256) void ball_kernel(const float* __restrict__ pos,
                                                   const int* __restrict__ fps_idx,
                                                   int* __restrict__ nbr_cnt,
                                                   int* __restrict__ nbr_idx) {
    __shared__ float px[NP], py[NP], pz[NP];
    __shared__ float cd2[4][CAP];
    __shared__ int cix[4][CAP];
    const int tid = threadIdx.x;
    const int wv = tid >> 6, lane = tid & 63;
    const int b = blockIdx.x >> 4;
    const int grp = blockIdx.x & 15;
    const float* p = pos + (size_t)b * NP * 3;
    for (int e = tid; e < NP; e += 256) {
        px[e] = p[e * 3 + 0];
        py[e] = p[e * 3 + 1];
        pz[e] = p[e * 3 + 2];
    }
    __syncthreads();
    for (int i = 0; i < 16; ++i) {
        const int s = grp * 64 + i * 4 + wv;
        const int cen = b * NS + s;
        const int ci = fps_idx[cen];
        const float cx = px[ci], cy = py[ci], cz = pz[ci];
        int cnt = 0;
        for (int it = 0; it < NP / 64; ++it) {
            const int j = it * 64 + lane;
            float d2 = dist2e(cx, cy, cz, px[j], py[j], pz[j]);
            bool in = (d2 <= 0.01f);  // f32(0.1*0.1)
            unsigned long long m = __ballot(in);
            if (in) {
                int slot = cnt + __popcll(m & ((1ull << lane) - 1ull));
                if (slot < CAP) { cd2[wv][slot] = d2; cix[wv][slot] = j; }
            }
            cnt += __popcll(m);
        }
        if (cnt > CAP) cnt = CAP;
        const int keep = cnt <= KN ? cnt : KN;
        if (lane == 0) nbr_cnt[cen] = keep;
        if (cnt <= KN) {
            if (lane < cnt) nbr_idx[(size_t)cen * KN + lane] = cix[wv][lane];
        } else {
            // exact K-nearest: rank by (d2, idx) lexicographic (top_k order)
            for (int e = lane; e < cnt; e += 64) {
                float d = cd2[wv][e];
                int id = cix[wv][e];
                int rank = 0;
                for (int q = 0; q < cnt; ++q) {
                    float dq = cd2[wv][q];
                    int iq = cix[wv][q];
                    rank += (dq < d || (dq == d && iq < id)) ? 1 : 0;
                }
                if (rank < KN) nbr_idx[(size_t)cen * KN + rank] = id;
            }
        }
    }
}

// ------- PointNetConv: block per center; W in regs, x_j/h in LDS (float4) ----
__global__ __launch_bounds__(256) void conv_kernel(const float* __restrict__ pos,
                                                   const float* __restrict__ x,
                                                   const int* __restrict__ fps_idx,
                                                   const int* __restrict__ nbr_cnt,
                                                   const int* __restrict__ nbr_idx,
                                                   const float* __restrict__ W1,
                                                   const float* __restrict__ b1,
                                                   const float* __restrict__ W2,
                                                   const float* __restrict__ b2,
                                                   const float* __restrict__ W3,
                                                   const float* __restrict__ b3,
                                                   float* __restrict__ out) {
    const int cen = blockIdx.x;
    const int b = cen >> 10;  // NS = 1024
    const int tid = threadIdx.x;
    const int lane = tid & 63;
    const int wv = tid >> 6;
    __shared__ __align__(16) float xj[KN][FIN];  // gathered x_j rows
    __shared__ __align__(16) float h1[KN][FIN];
    __shared__ __align__(16) float h2[KN][FIN];
    __shared__ float dpx[KN], dpy[KN], dpz[KN];
    __shared__ int jr[KN];
    __shared__ float omax[128];
    const int C = nbr_cnt[cen];
    const int ci = fps_idx[cen];
    const float* pb = pos + (size_t)b * NP * 3;
    if (tid < KN && tid < C) {
        int j = nbr_idx[(size_t)cen * KN + tid];
        jr[tid] = b * NP + j;
        float cx = pb[ci * 3 + 0], cy = pb[ci * 3 + 1], cz = pb[ci * 3 + 2];
        dpx[tid] = __fsub_rn(pb[j * 3 + 0], cx);
        dpy[tid] = __fsub_rn(pb[j * 3 + 1], cy);
        dpz[tid] = __fsub_rn(pb[j * 3 + 2], cz);
    }
    __syncthreads();
    for (int row = wv; row < C; row += 4) {
        xj[row][lane] = x[(size_t)jr[row] * FIN + lane];
    }
    __syncthreads();
    const int c = lane;
    const int pg = wv;
    {  // layer 1
        float w1r[FIN];
#pragma unroll
        for (int f = 0; f < FIN; ++f) w1r[f] = W1[f * 64 + c];
        const float w1x = W1[64 * 64 + c];
        const float w1y = W1[65 * 64 + c];
        const float w1z = W1[66 * 64 + c];
        const float bb = b1[c];
        for (int p = pg; p < C; p += 4) {
            float acc = bb + dpx[p] * w1x + dpy[p] * w1y + dpz[p] * w1z;
#pragma unroll
            for (int f4 = 0; f4 < FIN / 4; ++f4) {
                float4 v = *(const float4*)&xj[p][f4 * 4];
                acc = fmaf(v.x, w1r[f4 * 4 + 0], acc);
                acc = fmaf(v.y, w1r[f4 * 4 + 1], acc);
                acc = fmaf(v.z, w1r[f4 * 4 + 2], acc);
                acc = fmaf(v.w, w1r[f4 * 4 + 3], acc);
            }
            h1[p][c] = acc > 0.f ? acc : 0.f;
        }
    }
    __syncthreads();
    {  // layer 2
        float w2r[FIN];
#pragma unroll
        for (int k = 0; k < FIN; ++k) w2r[k] = W2[k * 64 + c];
        const float bb = b2[c];
        for (int p = pg; p < C; p += 4) {
            float acc = bb;
#pragma unroll
            for (int f4 = 0; f4 < FIN / 4; ++f4) {
                float4 v = *(const float4*)&h1[p][f4 * 4];
                acc = fmaf(v.x, w2r[f4 * 4 + 0], acc);
                acc = fmaf(v.y, w2r[f4 * 4 + 1], acc);
                acc = fmaf(v.z, w2r[f4 * 4 + 2], acc);
                acc = fmaf(v.w, w2r[f4 * 4 + 3], acc);
            }
            h2[p][c] = acc > 0.f ? acc : 0.f;
        }
    }
    __syncthreads();
    const int o = tid & 127;
    const int g2 = tid >> 7;
    {  // layer 3 + max aggregation
        float w3r[FIN];
#pragma unroll
        for (int k = 0; k < FIN; ++k) w3r[k] = W3[k * 128 + o];
        const float bb = b3[o];
        float mx = -INFINITY;
        for (int p = g2; p < C; p += 2) {
            float acc = bb;
#pragma unroll
            for (int f4 = 0; f4 < FIN / 4; ++f4) {
                float4 v = *(const float4*)&h2[p][f4 * 4];
                acc = fmaf(v.x, w3r[f4 * 4 + 0], acc);
                acc = fmaf(v.y, w3r[f4 * 4 + 1], acc);
                acc = fmaf(v.z, w3r[f4 * 4 + 2], acc);
                acc = fmaf(v.w, w3r[f4 * 4 + 3], acc);
            }
            acc = acc > 0.f ? acc : 0.f;
            mx = mx > acc ? mx : acc;
        }
        if (g2 == 0) omax[o] = mx;
        __syncthreads();
        if (g2 == 1) {
            float other = omax[o];
            mx = mx > other ? mx : other;
            out[(size_t)cen * 128 + o] = mx;
        }
    }
}

extern "C" void kernel_launch(void* const* d_in, const int* in_sizes, int n_in,
                              void* d_out, int out_size, void* d_ws, size_t ws_size,
                              hipStream_t stream) {
    const float* x   = (const float*)d_in[0];
    const float* pos = (const float*)d_in[1];
    const float* W1  = (const float*)d_in[3];
    const float* b1  = (const float*)d_in[4];
    const float* W2  = (const float*)d_in[5];
    const float* b2  = (const float*)d_in[6];
    const float* W3  = (const float*)d_in[7];
    const float* b3  = (const float*)d_in[8];
    float* out = (float*)d_out;
    char* ws = (char*)d_ws;
    int* fps_idx = (int*)(ws);                     // 16384 * 4 B
    int* nbr_cnt = (int*)(ws + 16384 * 4);         // 16384 * 4 B
    int* nbr_idx = (int*)(ws + 16384 * 8);         // 16384 * 64 * 4 B = 4 MB
    float* out_feat  = out;                         // [16384][128]
    float* out_pos   = out + (size_t)16384 * 128;   // [16384][3]
    float* out_batch = out + (size_t)16384 * 131;   // [16384]
    fps_kernel<<<NB / 2, 256, 0, stream>>>(pos, fps_idx, out_pos, out_batch);
    ball_kernel<<<NB * 16, 256, 0, stream>>>(pos, fps_idx, nbr_cnt, nbr_idx);
    conv_kernel<<<NB * NS, 256, 0, stream>>>(pos, x, fps_idx, nbr_cnt, nbr_idx,
                                             W1, b1, W2, b2, W3, b3, out_feat);
}

// Round 8
// 1489.222 us; speedup vs baseline: 1.4165x; 1.4165x over previous
//
#include <hip/hip_runtime.h>
#include <hip/hip_bf16.h>
#include <math.h>

// PointNet++ SAModule: FPS -> ball query -> PointNetConv(MLP, max-agg)
// B=16, N=4096, S=1024, K=64, r=0.1, MLP 67->64->64->128.
// Selection decisions (FPS argmax, ball membership, top-K) bit-exact vs numpy.
// R8: FPS = 2 clouds per block split BY WAVES (waves 0-3 cloud A, 4-7 cloud B),
// 8 blocks. Per-wave code identical to R5 (proven 795us/16CU). Mechanism: 2
// waves/SIMD -> hardware wave scheduler overlaps the two clouds' dependency
// stalls (m114 TLP), which R7's in-stream ILP failed to do. ball/conv untouched.

#define NB 16
#define NP 4096
#define FIN 64
#define NS 1024
#define KN 64
#define CAP 256

__device__ __forceinline__ float dist2e(float ax, float ay, float az,
                                        float bx, float by, float bz) {
    float dx = __fsub_rn(ax, bx);
    float dy = __fsub_rn(ay, by);
    float dz = __fsub_rn(az, bz);
    return __fadd_rn(__fadd_rn(__fmul_rn(dx, dx), __fmul_rn(dy, dy)),
                     __fmul_rn(dz, dz));
}

// One DPP row-rotate reduce level on a packed u64 key (max). CTRL literal:
// 0x121=ror:1 0x122=ror:2 0x124=ror:4 0x128=ror:8. (R5-proven, bit-exact.)
#define DPP_KEY_MAX(k, CTRL)                                                   \
    do {                                                                       \
        int _lo = (int)(unsigned)((k) & 0xFFFFFFFFull);                        \
        int _hi = (int)(unsigned)((k) >> 32);                                  \
        int _plo = __builtin_amdgcn_update_dpp(_lo, _lo, CTRL, 0xF, 0xF, false);\
        int _phi = __builtin_amdgcn_update_dpp(_hi, _hi, CTRL, 0xF, 0xF, false);\
        unsigned long long _nk =                                               \
            ((unsigned long long)(unsigned)_phi << 32) | (unsigned)_plo;       \
        if (_nk > (k)) (k) = _nk;                                              \
    } while (0)

// Full wave reduce (max) of packed u64 key: 4 DPP row levels + xor16 + xor32.
#define WAVE_KEY_MAX(k)                                                        \
    do {                                                                       \
        DPP_KEY_MAX(k, 0x121);                                                 \
        DPP_KEY_MAX(k, 0x122);                                                 \
        DPP_KEY_MAX(k, 0x124);                                                 \
        DPP_KEY_MAX(k, 0x128);                                                 \
        {                                                                      \
            int _lo = (int)(unsigned)((k) & 0xFFFFFFFFull);                    \
            int _hi = (int)(unsigned)((k) >> 32);                              \
            int _plo = __builtin_amdgcn_ds_swizzle(_lo, 0x401F);               \
            int _phi = __builtin_amdgcn_ds_swizzle(_hi, 0x401F);               \
            unsigned long long _nk =                                           \
                ((unsigned long long)(unsigned)_phi << 32) | (unsigned)_plo;   \
            if (_nk > (k)) (k) = _nk;                                          \
        }                                                                      \
        {                                                                      \
            unsigned long long _nk = __shfl_xor((k), 32, 64);                  \
            if (_nk > (k)) (k) = _nk;                                          \
        }                                                                      \
    } while (0)

// ---- FPS: 8 blocks x 512 thr; waves 0-3 = cloud A, waves 4-7 = cloud B -----
__global__ __launch_bounds__(512, 2) void fps_kernel(
        const float* __restrict__ pos, int* __restrict__ fps_idx,
        float* __restrict__ out_pos, float* __restrict__ out_batch) {
    const int blk = blockIdx.x;            // 0..7
    const int tid = threadIdx.x;           // 0..511
    const int wv = tid >> 6;               // 0..7
    const int half = wv >> 2;              // 0 = cloud A, 1 = cloud B
    const int wvL = wv & 3;                // wave index within half
    const int tloc = tid & 255;            // thread index within half
    const int b = blk * 2 + half;          // this half's cloud
    __shared__ float px[2][NP], py[2][NP], pz[2][NP];
    __shared__ __align__(16) float bc[2][2][4][8];  // [buf][half][wave][slot]
    const float* p = pos + (size_t)b * NP * 3;
    float lx[16], ly[16], lz[16], md[16];
#pragma unroll
    for (int i = 0; i < 16; ++i) {
        int j = tloc + (i << 8);
        float x = p[j * 3 + 0];
        float y = p[j * 3 + 1];
        float z = p[j * 3 + 2];
        px[half][j] = x; py[half][j] = y; pz[half][j] = z;
        lx[i] = x; ly[i] = y; lz[i] = z;
        md[i] = INFINITY;
    }
    __syncthreads();
    if (tloc == 0) {
        fps_idx[b * NS] = 0;
        out_pos[(size_t)(b * NS) * 3 + 0] = px[half][0];
        out_pos[(size_t)(b * NS) * 3 + 1] = py[half][0];
        out_pos[(size_t)(b * NS) * 3 + 2] = pz[half][0];
    }
    float cx = px[half][0], cy = py[half][0], cz = pz[half][0];
    for (int s = 1; s < NS; ++s) {
        // local md update + per-lane argmax (strict >, ascending i => lowest
        // index on tie, matching np.argmax first-occurrence)
        float bv = -1.0f;
        int bi = 0;
#pragma unroll
        for (int i = 0; i < 16; ++i) {
            float d = dist2e(lx[i], ly[i], lz[i], cx, cy, cz);
            float m = md[i];
            m = d < m ? d : m;   // jnp.minimum (exact)
            md[i] = m;
            bool take = (m > bv);
            bv = take ? m : bv;
            bi = take ? (tloc + (i << 8)) : bi;
        }
        // pack: positive-f32 bits order-isomorphic; ~idx => tie -> lower idx
        unsigned long long key =
            ((unsigned long long)__float_as_uint(bv) << 32) |
            (unsigned)(~(unsigned)bi);
        WAVE_KEY_MAX(key);
        const int buf = s & 1;  // double buffer -> one barrier per step
        if ((tid & 63) == 0) {
            int wi = (int)(~(unsigned)(key & 0xFFFFFFFFull));
            bc[buf][half][wvL][0] =
                __uint_as_float((unsigned)(key & 0xFFFFFFFFull));
            bc[buf][half][wvL][1] = __uint_as_float((unsigned)(key >> 32));
            bc[buf][half][wvL][2] = px[half][wi];
            bc[buf][half][wvL][3] = py[half][wi];
            bc[buf][half][wvL][4] = pz[half][wi];
        }
        __syncthreads();
        // all lanes of this half: select best of its 4 wave candidates
        unsigned long long bk;
        float bx, by, bz;
        {
            float4 e = *(const float4*)&bc[buf][half][0][0];
            bk = ((unsigned long long)__float_as_uint(e.y) << 32) |
                 __float_as_uint(e.x);
            bx = e.z; by = e.w; bz = bc[buf][half][0][4];
        }
#pragma unroll
        for (int w = 1; w < 4; ++w) {
            float4 e = *(const float4*)&bc[buf][half][w][0];
            unsigned long long k2 =
                ((unsigned long long)__float_as_uint(e.y) << 32) |
                __float_as_uint(e.x);
            float z2 = bc[buf][half][w][4];
            bool take = (k2 > bk);
            bk = take ? k2 : bk;
            bx = take ? e.z : bx;
            by = take ? e.w : by;
            bz = take ? z2 : bz;
        }
        const int cur = (int)(~(unsigned)(bk & 0xFFFFFFFFull));
        cx = bx; cy = by; cz = bz;
        if (tloc == 0) {
            fps_idx[b * NS + s] = cur;
            out_pos[(size_t)(b * NS + s) * 3 + 0] = bx;
            out_pos[(size_t)(b * NS + s) * 3 + 1] = by;
            out_pos[(size_t)(b * NS + s) * 3 + 2] = bz;
        }
    }
    for (int s = tloc; s < NS; s += 256) out_batch[b * NS + s] = (float)b;
}

// ------------- ball query: 16 blocks/cloud, 64 centers/block, wave/center ----
__global__ __launch_bounds__(256) void ball_kernel(const float* __restrict__ pos,
                                                   const int* __restrict__ fps_idx,
                                                   int* __restrict__ nbr_cnt,
                                                   int* __restrict__ nbr_idx) {
    __shared__ float px[NP], py[NP], pz[NP];
    __shared__ float cd2[4][CAP];
    __shared__ int cix[4][CAP];
    const int tid = threadIdx.x;
    const int wv = tid >> 6, lane = tid & 63;
    const int b = blockIdx.x >> 4;
    const int grp = blockIdx.x & 15;
    const float* p = pos + (size_t)b * NP * 3;
    for (int e = tid; e < NP; e += 256) {
        px[e] = p[e * 3 + 0];
        py[e] = p[e * 3 + 1];
        pz[e] = p[e * 3 + 2];
    }
    __syncthreads();
    for (int i = 0; i < 16; ++i) {
        const int s = grp * 64 + i * 4 + wv;
        const int cen = b * NS + s;
        const int ci = fps_idx[cen];
        const float cx = px[ci], cy = py[ci], cz = pz[ci];
        int cnt = 0;
        for (int it = 0; it < NP / 64; ++it) {
            const int j = it * 64 + lane;
            float d2 = dist2e(cx, cy, cz, px[j], py[j], pz[j]);
            bool in = (d2 <= 0.01f);  // f32(0.1*0.1)
            unsigned long long m = __ballot(in);
            if (in) {
                int slot = cnt + __popcll(m & ((1ull << lane) - 1ull));
                if (slot < CAP) { cd2[wv][slot] = d2; cix[wv][slot] = j; }
            }
            cnt += __popcll(m);
        }
        if (cnt > CAP) cnt = CAP;
        const int keep = cnt <= KN ? cnt : KN;
        if (lane == 0) nbr_cnt[cen] = keep;
        if (cnt <= KN) {
            if (lane < cnt) nbr_idx[(size_t)cen * KN + lane] = cix[wv][lane];
        } else {
            // exact K-nearest: rank by (d2, idx) lexicographic (top_k order)
            for (int e = lane; e < cnt; e += 64) {
                float d = cd2[wv][e];
                int id = cix[wv][e];
                int rank = 0;
                for (int q = 0; q < cnt; ++q) {
                    float dq = cd2[wv][q];
                    int iq = cix[wv][q];
                    rank += (dq < d || (dq == d && iq < id)) ? 1 : 0;
                }
                if (rank < KN) nbr_idx[(size_t)cen * KN + rank] = id;
            }
        }
    }
}

// ------- PointNetConv: block per center; W in regs, x_j/h in LDS (float4) ----
__global__ __launch_bounds__(256) void conv_kernel(const float* __restrict__ pos,
                                                   const float* __restrict__ x,
                                                   const int* __restrict__ fps_idx,
                                                   const int* __restrict__ nbr_cnt,
                                                   const int* __restrict__ nbr_idx,
                                                   const float* __restrict__ W1,
                                                   const float* __restrict__ b1,
                                                   const float* __restrict__ W2,
                                                   const float* __restrict__ b2,
                                                   const float* __restrict__ W3,
                                                   const float* __restrict__ b3,
                                                   float* __restrict__ out) {
    const int cen = blockIdx.x;
    const int b = cen >> 10;  // NS = 1024
    const int tid = threadIdx.x;
    const int lane = tid & 63;
    const int wv = tid >> 6;
    __shared__ __align__(16) float xj[KN][FIN];  // gathered x_j rows
    __shared__ __align__(16) float h1[KN][FIN];
    __shared__ __align__(16) float h2[KN][FIN];
    __shared__ float dpx[KN], dpy[KN], dpz[KN];
    __shared__ int jr[KN];
    __shared__ float omax[128];
    const int C = nbr_cnt[cen];
    const int ci = fps_idx[cen];
    const float* pb = pos + (size_t)b * NP * 3;
    if (tid < KN && tid < C) {
        int j = nbr_idx[(size_t)cen * KN + tid];
        jr[tid] = b * NP + j;
        float cx = pb[ci * 3 + 0], cy = pb[ci * 3 + 1], cz = pb[ci * 3 + 2];
        dpx[tid] = __fsub_rn(pb[j * 3 + 0], cx);
        dpy[tid] = __fsub_rn(pb[j * 3 + 1], cy);
        dpz[tid] = __fsub_rn(pb[j * 3 + 2], cz);
    }
    __syncthreads();
    for (int row = wv; row < C; row += 4) {
        xj[row][lane] = x[(size_t)jr[row] * FIN + lane];
    }
    __syncthreads();
    const int c = lane;
    const int pg = wv;
    {  // layer 1
        float w1r[FIN];
#pragma unroll
        for (int f = 0; f < FIN; ++f) w1r[f] = W1[f * 64 + c];
        const float w1x = W1[64 * 64 + c];
        const float w1y = W1[65 * 64 + c];
        const float w1z = W1[66 * 64 + c];
        const float bb = b1[c];
        for (int p = pg; p < C; p += 4) {
            float acc = bb + dpx[p] * w1x + dpy[p] * w1y + dpz[p] * w1z;
#pragma unroll
            for (int f4 = 0; f4 < FIN / 4; ++f4) {
                float4 v = *(const float4*)&xj[p][f4 * 4];
                acc = fmaf(v.x, w1r[f4 * 4 + 0], acc);
                acc = fmaf(v.y, w1r[f4 * 4 + 1], acc);
                acc = fmaf(v.z, w1r[f4 * 4 + 2], acc);
                acc = fmaf(v.w, w1r[f4 * 4 + 3], acc);
            }
            h1[p][c] = acc > 0.f ? acc : 0.f;
        }
    }
    __syncthreads();
    {  // layer 2
        float w2r[FIN];
#pragma unroll
        for (int k = 0; k < FIN; ++k) w2r[k] = W2[k * 64 + c];
        const float bb = b2[c];
        for (int p = pg; p < C; p += 4) {
            float acc = bb;
#pragma unroll
            for (int f4 = 0; f4 < FIN / 4; ++f4) {
                float4 v = *(const float4*)&h1[p][f4 * 4];
                acc = fmaf(v.x, w2r[f4 * 4 + 0], acc);
                acc = fmaf(v.y, w2r[f4 * 4 + 1], acc);
                acc = fmaf(v.z, w2r[f4 * 4 + 2], acc);
                acc = fmaf(v.w, w2r[f4 * 4 + 3], acc);
            }
            h2[p][c] = acc > 0.f ? acc : 0.f;
        }
    }
    __syncthreads();
    const int o = tid & 127;
    const int g2 = tid >> 7;
    {  // layer 3 + max aggregation
        float w3r[FIN];
#pragma unroll
        for (int k = 0; k < FIN; ++k) w3r[k] = W3[k * 128 + o];
        const float bb = b3[o];
        float mx = -INFINITY;
        for (int p = g2; p < C; p += 2) {
            float acc = bb;
#pragma unroll
            for (int f4 = 0; f4 < FIN / 4; ++f4) {
                float4 v = *(const float4*)&h2[p][f4 * 4];
                acc = fmaf(v.x, w3r[f4 * 4 + 0], acc);
                acc = fmaf(v.y, w3r[f4 * 4 + 1], acc);
                acc = fmaf(v.z, w3r[f4 * 4 + 2], acc);
                acc = fmaf(v.w, w3r[f4 * 4 + 3], acc);
            }
            acc = acc > 0.f ? acc : 0.f;
            mx = mx > acc ? mx : acc;
        }
        if (g2 == 0) omax[o] = mx;
        __syncthreads();
        if (g2 == 1) {
            float other = omax[o];
            mx = mx > other ? mx : other;
            out[(size_t)cen * 128 + o] = mx;
        }
    }
}

extern "C" void kernel_launch(void* const* d_in, const int* in_sizes, int n_in,
                              void* d_out, int out_size, void* d_ws, size_t ws_size,
                              hipStream_t stream) {
    const float* x   = (const float*)d_in[0];
    const float* pos = (const float*)d_in[1];
    const float* W1  = (const float*)d_in[3];
    const float* b1  = (const float*)d_in[4];
    const float* W2  = (const float*)d_in[5];
    const float* b2  = (const float*)d_in[6];
    const float* W3  = (const float*)d_in[7];
    const float* b3  = (const float*)d_in[8];
    float* out = (float*)d_out;
    char* ws = (char*)d_ws;
    int* fps_idx = (int*)(ws);                     // 16384 * 4 B
    int* nbr_cnt = (int*)(ws + 16384 * 4);         // 16384 * 4 B
    int* nbr_idx = (int*)(ws + 16384 * 8);         // 16384 * 64 * 4 B = 4 MB
    float* out_feat  = out;                         // [16384][128]
    float* out_pos   = out + (size_t)16384 * 128;   // [16384][3]
    float* out_batch = out + (size_t)16384 * 131;   // [16384]
    fps_kernel<<<NB / 2, 512, 0, stream>>>(pos, fps_idx, out_pos, out_batch);
    ball_kernel<<<NB * 16, 256, 0, stream>>>(pos, fps_idx, nbr_cnt, nbr_idx);
    conv_kernel<<<NB * NS, 256, 0, stream>>>(pos, x, fps_idx, nbr_cnt, nbr_idx,
                                             W1, b1, W2, b2, W3, b3, out_feat);
}

// Round 9
// 1265.977 us; speedup vs baseline: 1.6663x; 1.1763x over previous
//
#include <hip/hip_runtime.h>
#include <hip/hip_bf16.h>
#include <math.h>

// PointNet++ SAModule: FPS -> ball query -> PointNetConv(MLP, max-agg)
// B=16, N=4096, S=1024, K=64, r=0.1, MLP 67->64->64->128.
// Selection decisions (FPS argmax, ball membership, top-K) bit-exact vs numpy.
// R9: FPS per-step critical path rebuilt: key-only pure-DPP ladder (R6-proven
// ctrls) -> lane63 -> v_readlane broadcast (no LDS round trips in reduce);
// winner lane self-identifies and writes key+xyz from registers (no pos LDS
// at all); per-step global stores -> LDS hist drained at end. 16 blocks.
// ball/conv byte-identical to R8.

#define NB 16
#define NP 4096
#define FIN 64
#define NS 1024
#define KN 64
#define CAP 256

__device__ __forceinline__ float dist2e(float ax, float ay, float az,
                                        float bx, float by, float bz) {
    float dx = __fsub_rn(ax, bx);
    float dy = __fsub_rn(ay, by);
    float dz = __fsub_rn(az, bz);
    return __fadd_rn(__fadd_rn(__fmul_rn(dx, dx), __fmul_rn(dy, dy)),
                     __fmul_rn(dz, dz));
}

// One DPP reduce level on packed u64 key (max), key-only (no payload).
// CTRL: 0x111=shr1 0x112=shr2 0x114=shr4 0x118=shr8 0x142=bcast15 0x143=bcast31
// (R6-proven bit-exact on gfx950). bound_ctrl=false + old=self.
#define DPP_KEY_MAX(k, CTRL)                                                   \
    do {                                                                       \
        int _lo = (int)(unsigned)((k) & 0xFFFFFFFFull);                        \
        int _hi = (int)(unsigned)((k) >> 32);                                  \
        int _plo = __builtin_amdgcn_update_dpp(_lo, _lo, CTRL, 0xF, 0xF, false);\
        int _phi = __builtin_amdgcn_update_dpp(_hi, _hi, CTRL, 0xF, 0xF, false);\
        unsigned long long _nk =                                               \
            ((unsigned long long)(unsigned)_phi << 32) | (unsigned)_plo;       \
        if (_nk > (k)) (k) = _nk;                                              \
    } while (0)

// ---------------- FPS: one block per cloud, 256 thr, 16 pts/thread ----------
__global__ __launch_bounds__(256) void fps_kernel(const float* __restrict__ pos,
                                                  int* __restrict__ fps_idx,
                                                  float* __restrict__ out_pos,
                                                  float* __restrict__ out_batch) {
    const int b = blockIdx.x;
    const int tid = threadIdx.x;
    const int wv = tid >> 6;
    __shared__ __align__(16) float4 hist[NS];       // {idx_bits, x, y, z}
    __shared__ __align__(16) float bc[2][4][8];     // [buf][wave]{lo,hi,x,y,z}
    const float* p = pos + (size_t)b * NP * 3;
    float lx[16], ly[16], lz[16], md[16];
#pragma unroll
    for (int i = 0; i < 16; ++i) {
        int j = tid + (i << 8);
        lx[i] = p[j * 3 + 0];
        ly[i] = p[j * 3 + 1];
        lz[i] = p[j * 3 + 2];
        md[i] = INFINITY;
    }
    const float c0x = p[0], c0y = p[1], c0z = p[2];
    float cx = c0x, cy = c0y, cz = c0z;
    for (int s = 1; s < NS; ++s) {
        // local md update + per-lane argmax with xyz carry (strict >, asc i
        // => lowest index on tie, matching np.argmax first-occurrence)
        float bv = -1.0f;
        int bi = 0;
        float wx = 0.f, wy = 0.f, wz = 0.f;
#pragma unroll
        for (int i = 0; i < 16; ++i) {
            float d = dist2e(lx[i], ly[i], lz[i], cx, cy, cz);
            float m = md[i];
            m = d < m ? d : m;   // jnp.minimum (exact)
            md[i] = m;
            bool take = (m > bv);
            bv = take ? m : bv;
            bi = take ? (tid + (i << 8)) : bi;
            wx = take ? lx[i] : wx;
            wy = take ? ly[i] : wy;
            wz = take ? lz[i] : wz;
        }
        // pack: positive-f32 bits order-isomorphic; ~idx => tie -> lower idx
        unsigned long long key =
            ((unsigned long long)__float_as_uint(bv) << 32) |
            (unsigned)(~(unsigned)bi);
        const unsigned long long my = key;
        // pure-DPP wave reduce -> lane 63, then readlane broadcast (no LDS)
        DPP_KEY_MAX(key, 0x111);
        DPP_KEY_MAX(key, 0x112);
        DPP_KEY_MAX(key, 0x114);
        DPP_KEY_MAX(key, 0x118);
        DPP_KEY_MAX(key, 0x142);
        DPP_KEY_MAX(key, 0x143);
        const unsigned kwlo =
            (unsigned)__builtin_amdgcn_readlane((int)(unsigned)(key & 0xFFFFFFFFull), 63);
        const unsigned kwhi =
            (unsigned)__builtin_amdgcn_readlane((int)(unsigned)(key >> 32), 63);
        const unsigned long long kw =
            ((unsigned long long)kwhi << 32) | kwlo;
        const int buf = s & 1;  // double buffer -> one barrier per step
        if (my == kw) {         // unique winner lane (idx embedded in key)
            bc[buf][wv][0] = __uint_as_float(kwlo);
            bc[buf][wv][1] = __uint_as_float(kwhi);
            bc[buf][wv][2] = wx;
            bc[buf][wv][3] = wy;
            bc[buf][wv][4] = wz;
        }
        __syncthreads();
        // all lanes: select best of the 4 wave candidates (key + xyz folded)
        unsigned long long bk;
        float bx, by, bz;
        {
            float4 e = *(const float4*)&bc[buf][0][0];
            bk = ((unsigned long long)__float_as_uint(e.y) << 32) |
                 __float_as_uint(e.x);
            bx = e.z; by = e.w; bz = bc[buf][0][4];
        }
#pragma unroll
        for (int w = 1; w < 4; ++w) {
            float4 e = *(const float4*)&bc[buf][w][0];
            unsigned long long k2 =
                ((unsigned long long)__float_as_uint(e.y) << 32) |
                __float_as_uint(e.x);
            float z2 = bc[buf][w][4];
            bool take = (k2 > bk);
            bk = take ? k2 : bk;
            bx = take ? e.z : bx;
            by = take ? e.w : by;
            bz = take ? z2 : bz;
        }
        const int cur = (int)(~(unsigned)(bk & 0xFFFFFFFFull));
        cx = bx; cy = by; cz = bz;
        if (tid == 0) {
            hist[s] = make_float4(__int_as_float(cur), bx, by, bz);
        }
    }
    __syncthreads();
    // drain hist -> global (step 0 = point 0 by definition)
    for (int s = tid; s < NS; s += 256) {
        if (s == 0) {
            fps_idx[b * NS] = 0;
            out_pos[(size_t)(b * NS) * 3 + 0] = c0x;
            out_pos[(size_t)(b * NS) * 3 + 1] = c0y;
            out_pos[(size_t)(b * NS) * 3 + 2] = c0z;
        } else {
            float4 e = hist[s];
            fps_idx[b * NS + s] = __float_as_int(e.x);
            out_pos[(size_t)(b * NS + s) * 3 + 0] = e.y;
            out_pos[(size_t)(b * NS + s) * 3 + 1] = e.z;
            out_pos[(size_t)(b * NS + s) * 3 + 2] = e.w;
        }
        out_batch[b * NS + s] = (float)b;
    }
}

// ------------- ball query: 16 blocks/cloud, 64 centers/block, wave/center ----
__global__ __launch_bounds__(256) void ball_kernel(const float* __restrict__ pos,
                                                   const int* __restrict__ fps_idx,
                                                   int* __restrict__ nbr_cnt,
                                                   int* __restrict__ nbr_idx) {
    __shared__ float px[NP], py[NP], pz[NP];
    __shared__ float cd2[4][CAP];
    __shared__ int cix[4][CAP];
    const int tid = threadIdx.x;
    const int wv = tid >> 6, lane = tid & 63;
    const int b = blockIdx.x >> 4;
    const int grp = blockIdx.x & 15;
    const float* p = pos + (size_t)b * NP * 3;
    for (int e = tid; e < NP; e += 256) {
        px[e] = p[e * 3 + 0];
        py[e] = p[e * 3 + 1];
        pz[e] = p[e * 3 + 2];
    }
    __syncthreads();
    for (int i = 0; i < 16; ++i) {
        const int s = grp * 64 + i * 4 + wv;
        const int cen = b * NS + s;
        const int ci = fps_idx[cen];
        const float cx = px[ci], cy = py[ci], cz = pz[ci];
        int cnt = 0;
        for (int it = 0; it < NP / 64; ++it) {
            const int j = it * 64 + lane;
            float d2 = dist2e(cx, cy, cz, px[j], py[j], pz[j]);
            bool in = (d2 <= 0.01f);  // f32(0.1*0.1)
            unsigned long long m = __ballot(in);
            if (in) {
                int slot = cnt + __popcll(m & ((1ull << lane) - 1ull));
                if (slot < CAP) { cd2[wv][slot] = d2; cix[wv][slot] = j; }
            }
            cnt += __popcll(m);
        }
        if (cnt > CAP) cnt = CAP;
        const int keep = cnt <= KN ? cnt : KN;
        if (lane == 0) nbr_cnt[cen] = keep;
        if (cnt <= KN) {
            if (lane < cnt) nbr_idx[(size_t)cen * KN + lane] = cix[wv][lane];
        } else {
            // exact K-nearest: rank by (d2, idx) lexicographic (top_k order)
            for (int e = lane; e < cnt; e += 64) {
                float d = cd2[wv][e];
                int id = cix[wv][e];
                int rank = 0;
                for (int q = 0; q < cnt; ++q) {
                    float dq = cd2[wv][q];
                    int iq = cix[wv][q];
                    rank += (dq < d || (dq == d && iq < id)) ? 1 : 0;
                }
                if (rank < KN) nbr_idx[(size_t)cen * KN + rank] = id;
            }
        }
    }
}

// ------- PointNetConv: block per center; W in regs, x_j/h in LDS (float4) ----
__global__ __launch_bounds__(256) void conv_kernel(const float* __restrict__ pos,
                                                   const float* __restrict__ x,
                                                   const int* __restrict__ fps_idx,
                                                   const int* __restrict__ nbr_cnt,
                                                   const int* __restrict__ nbr_idx,
                                                   const float* __restrict__ W1,
                                                   const float* __restrict__ b1,
                                                   const float* __restrict__ W2,
                                                   const float* __restrict__ b2,
                                                   const float* __restrict__ W3,
                                                   const float* __restrict__ b3,
                                                   float* __restrict__ out) {
    const int cen = blockIdx.x;
    const int b = cen >> 10;  // NS = 1024
    const int tid = threadIdx.x;
    const int lane = tid & 63;
    const int wv = tid >> 6;
    __shared__ __align__(16) float xj[KN][FIN];  // gathered x_j rows
    __shared__ __align__(16) float h1[KN][FIN];
    __shared__ __align__(16) float h2[KN][FIN];
    __shared__ float dpx[KN], dpy[KN], dpz[KN];
    __shared__ int jr[KN];
    __shared__ float omax[128];
    const int C = nbr_cnt[cen];
    const int ci = fps_idx[cen];
    const float* pb = pos + (size_t)b * NP * 3;
    if (tid < KN && tid < C) {
        int j = nbr_idx[(size_t)cen * KN + tid];
        jr[tid] = b * NP + j;
        float cx = pb[ci * 3 + 0], cy = pb[ci * 3 + 1], cz = pb[ci * 3 + 2];
        dpx[tid] = __fsub_rn(pb[j * 3 + 0], cx);
        dpy[tid] = __fsub_rn(pb[j * 3 + 1], cy);
        dpz[tid] = __fsub_rn(pb[j * 3 + 2], cz);
    }
    __syncthreads();
    for (int row = wv; row < C; row += 4) {
        xj[row][lane] = x[(size_t)jr[row] * FIN + lane];
    }
    __syncthreads();
    const int c = lane;
    const int pg = wv;
    {  // layer 1
        float w1r[FIN];
#pragma unroll
        for (int f = 0; f < FIN; ++f) w1r[f] = W1[f * 64 + c];
        const float w1x = W1[64 * 64 + c];
        const float w1y = W1[65 * 64 + c];
        const float w1z = W1[66 * 64 + c];
        const float bb = b1[c];
        for (int p = pg; p < C; p += 4) {
            float acc = bb + dpx[p] * w1x + dpy[p] * w1y + dpz[p] * w1z;
#pragma unroll
            for (int f4 = 0; f4 < FIN / 4; ++f4) {
                float4 v = *(const float4*)&xj[p][f4 * 4];
                acc = fmaf(v.x, w1r[f4 * 4 + 0], acc);
                acc = fmaf(v.y, w1r[f4 * 4 + 1], acc);
                acc = fmaf(v.z, w1r[f4 * 4 + 2], acc);
                acc = fmaf(v.w, w1r[f4 * 4 + 3], acc);
            }
            h1[p][c] = acc > 0.f ? acc : 0.f;
        }
    }
    __syncthreads();
    {  // layer 2
        float w2r[FIN];
#pragma unroll
        for (int k = 0; k < FIN; ++k) w2r[k] = W2[k * 64 + c];
        const float bb = b2[c];
        for (int p = pg; p < C; p += 4) {
            float acc = bb;
#pragma unroll
            for (int f4 = 0; f4 < FIN / 4; ++f4) {
                float4 v = *(const float4*)&h1[p][f4 * 4];
                acc = fmaf(v.x, w2r[f4 * 4 + 0], acc);
                acc = fmaf(v.y, w2r[f4 * 4 + 1], acc);
                acc = fmaf(v.z, w2r[f4 * 4 + 2], acc);
                acc = fmaf(v.w, w2r[f4 * 4 + 3], acc);
            }
            h2[p][c] = acc > 0.f ? acc : 0.f;
        }
    }
    __syncthreads();
    const int o = tid & 127;
    const int g2 = tid >> 7;
    {  // layer 3 + max aggregation
        float w3r[FIN];
#pragma unroll
        for (int k = 0; k < FIN; ++k) w3r[k] = W3[k * 128 + o];
        const float bb = b3[o];
        float mx = -INFINITY;
        for (int p = g2; p < C; p += 2) {
            float acc = bb;
#pragma unroll
            for (int f4 = 0; f4 < FIN / 4; ++f4) {
                float4 v = *(const float4*)&h2[p][f4 * 4];
                acc = fmaf(v.x, w3r[f4 * 4 + 0], acc);
                acc = fmaf(v.y, w3r[f4 * 4 + 1], acc);
                acc = fmaf(v.z, w3r[f4 * 4 + 2], acc);
                acc = fmaf(v.w, w3r[f4 * 4 + 3], acc);
            }
            acc = acc > 0.f ? acc : 0.f;
            mx = mx > acc ? mx : acc;
        }
        if (g2 == 0) omax[o] = mx;
        __syncthreads();
        if (g2 == 1) {
            float other = omax[o];
            mx = mx > other ? mx : other;
            out[(size_t)cen * 128 + o] = mx;
        }
    }
}

extern "C" void kernel_launch(void* const* d_in, const int* in_sizes, int n_in,
                              void* d_out, int out_size, void* d_ws, size_t ws_size,
                              hipStream_t stream) {
    const float* x   = (const float*)d_in[0];
    const float* pos = (const float*)d_in[1];
    const float* W1  = (const float*)d_in[3];
    const float* b1  = (const float*)d_in[4];
    const float* W2  = (const float*)d_in[5];
    const float* b2  = (const float*)d_in[6];
    const float* W3  = (const float*)d_in[7];
    const float* b3  = (const float*)d_in[8];
    float* out = (float*)d_out;
    char* ws = (char*)d_ws;
    int* fps_idx = (int*)(ws);                     // 16384 * 4 B
    int* nbr_cnt = (int*)(ws + 16384 * 4);         // 16384 * 4 B
    int* nbr_idx = (int*)(ws + 16384 * 8);         // 16384 * 64 * 4 B = 4 MB
    float* out_feat  = out;                         // [16384][128]
    float* out_pos   = out + (size_t)16384 * 128;   // [16384][3]
    float* out_batch = out + (size_t)16384 * 131;   // [16384]
    fps_kernel<<<NB, 256, 0, stream>>>(pos, fps_idx, out_pos, out_batch);
    ball_kernel<<<NB * 16, 256, 0, stream>>>(pos, fps_idx, nbr_cnt, nbr_idx);
    conv_kernel<<<NB * NS, 256, 0, stream>>>(pos, x, fps_idx, nbr_cnt, nbr_idx,
                                             W1, b1, W2, b2, W3, b3, out_feat);
}

// Round 10
// 1140.756 us; speedup vs baseline: 1.8493x; 1.1098x over previous
//
#include <hip/hip_runtime.h>
#include <hip/hip_bf16.h>
#include <math.h>

// PointNet++ SAModule: FPS -> ball query -> PointNetConv(MLP, max-agg)
// B=16, N=4096, S=1024, K=64, r=0.1, MLP 67->64->64->128.
// Selection (FPS argmax, ball membership, top-K) bit-exact vs numpy (fp32
// __f*_rn). R10: conv rewritten on MFMA 16x16x32 bf16 (tolerance 0.3 >> bf16
// err ~0.1): per block 8 centers, rows padded to 64 = 4 wave-private 16-row
// tiles, W frags in regs, L1 A-frags gathered straight from global x, h1/h2
// bf16 LDS with XOR swizzle both sides. fps/ball identical to R9.

#define NB 16
#define NP 4096
#define FIN 64
#define NS 1024
#define KN 64
#define CAP 256
#define CPB 8

typedef __attribute__((ext_vector_type(8))) short bf16x8;
typedef __attribute__((ext_vector_type(4))) float f32x4;

__device__ __forceinline__ float dist2e(float ax, float ay, float az,
                                        float bx, float by, float bz) {
    float dx = __fsub_rn(ax, bx);
    float dy = __fsub_rn(ay, by);
    float dz = __fsub_rn(az, bz);
    return __fadd_rn(__fadd_rn(__fmul_rn(dx, dx), __fmul_rn(dy, dy)),
                     __fmul_rn(dz, dz));
}

__device__ __forceinline__ short f2bf(float f) {  // RNE fp32 -> bf16 bits
    unsigned u = __float_as_uint(f);
    unsigned r = (u + 0x7FFFu + ((u >> 16) & 1u)) >> 16;
    return (short)r;
}

// One DPP reduce level on packed u64 key (max), key-only.
#define DPP_KEY_MAX(k, CTRL)                                                   \
    do {                                                                       \
        int _lo = (int)(unsigned)((k) & 0xFFFFFFFFull);                        \
        int _hi = (int)(unsigned)((k) >> 32);                                  \
        int _plo = __builtin_amdgcn_update_dpp(_lo, _lo, CTRL, 0xF, 0xF, false);\
        int _phi = __builtin_amdgcn_update_dpp(_hi, _hi, CTRL, 0xF, 0xF, false);\
        unsigned long long _nk =                                               \
            ((unsigned long long)(unsigned)_phi << 32) | (unsigned)_plo;       \
        if (_nk > (k)) (k) = _nk;                                              \
    } while (0)

// ---------------- FPS (R9, unchanged): one block/cloud, 256 thr -------------
__global__ __launch_bounds__(256) void fps_kernel(const float* __restrict__ pos,
                                                  int* __restrict__ fps_idx,
                                                  float* __restrict__ out_pos,
                                                  float* __restrict__ out_batch) {
    const int b = blockIdx.x;
    const int tid = threadIdx.x;
    const int wv = tid >> 6;
    __shared__ __align__(16) float4 hist[NS];
    __shared__ __align__(16) float bc[2][4][8];
    const float* p = pos + (size_t)b * NP * 3;
    float lx[16], ly[16], lz[16], md[16];
#pragma unroll
    for (int i = 0; i < 16; ++i) {
        int j = tid + (i << 8);
        lx[i] = p[j * 3 + 0];
        ly[i] = p[j * 3 + 1];
        lz[i] = p[j * 3 + 2];
        md[i] = INFINITY;
    }
    const float c0x = p[0], c0y = p[1], c0z = p[2];
    float cx = c0x, cy = c0y, cz = c0z;
    for (int s = 1; s < NS; ++s) {
        float bv = -1.0f;
        int bi = 0;
        float wx = 0.f, wy = 0.f, wz = 0.f;
#pragma unroll
        for (int i = 0; i < 16; ++i) {
            float d = dist2e(lx[i], ly[i], lz[i], cx, cy, cz);
            float m = md[i];
            m = d < m ? d : m;   // jnp.minimum (exact)
            md[i] = m;
            bool take = (m > bv);
            bv = take ? m : bv;
            bi = take ? (tid + (i << 8)) : bi;
            wx = take ? lx[i] : wx;
            wy = take ? ly[i] : wy;
            wz = take ? lz[i] : wz;
        }
        unsigned long long key =
            ((unsigned long long)__float_as_uint(bv) << 32) |
            (unsigned)(~(unsigned)bi);
        const unsigned long long my = key;
        DPP_KEY_MAX(key, 0x111);
        DPP_KEY_MAX(key, 0x112);
        DPP_KEY_MAX(key, 0x114);
        DPP_KEY_MAX(key, 0x118);
        DPP_KEY_MAX(key, 0x142);
        DPP_KEY_MAX(key, 0x143);
        const unsigned kwlo =
            (unsigned)__builtin_amdgcn_readlane((int)(unsigned)(key & 0xFFFFFFFFull), 63);
        const unsigned kwhi =
            (unsigned)__builtin_amdgcn_readlane((int)(unsigned)(key >> 32), 63);
        const unsigned long long kw = ((unsigned long long)kwhi << 32) | kwlo;
        const int buf = s & 1;
        if (my == kw) {
            bc[buf][wv][0] = __uint_as_float(kwlo);
            bc[buf][wv][1] = __uint_as_float(kwhi);
            bc[buf][wv][2] = wx;
            bc[buf][wv][3] = wy;
            bc[buf][wv][4] = wz;
        }
        __syncthreads();
        unsigned long long bk;
        float bx, by, bz;
        {
            float4 e = *(const float4*)&bc[buf][0][0];
            bk = ((unsigned long long)__float_as_uint(e.y) << 32) |
                 __float_as_uint(e.x);
            bx = e.z; by = e.w; bz = bc[buf][0][4];
        }
#pragma unroll
        for (int w = 1; w < 4; ++w) {
            float4 e = *(const float4*)&bc[buf][w][0];
            unsigned long long k2 =
                ((unsigned long long)__float_as_uint(e.y) << 32) |
                __float_as_uint(e.x);
            float z2 = bc[buf][w][4];
            bool take = (k2 > bk);
            bk = take ? k2 : bk;
            bx = take ? e.z : bx;
            by = take ? e.w : by;
            bz = take ? z2 : bz;
        }
        const int cur = (int)(~(unsigned)(bk & 0xFFFFFFFFull));
        cx = bx; cy = by; cz = bz;
        if (tid == 0) hist[s] = make_float4(__int_as_float(cur), bx, by, bz);
    }
    __syncthreads();
    for (int s = tid; s < NS; s += 256) {
        if (s == 0) {
            fps_idx[b * NS] = 0;
            out_pos[(size_t)(b * NS) * 3 + 0] = c0x;
            out_pos[(size_t)(b * NS) * 3 + 1] = c0y;
            out_pos[(size_t)(b * NS) * 3 + 2] = c0z;
        } else {
            float4 e = hist[s];
            fps_idx[b * NS + s] = __float_as_int(e.x);
            out_pos[(size_t)(b * NS + s) * 3 + 0] = e.y;
            out_pos[(size_t)(b * NS + s) * 3 + 1] = e.z;
            out_pos[(size_t)(b * NS + s) * 3 + 2] = e.w;
        }
        out_batch[b * NS + s] = (float)b;
    }
}

// ------------- ball query (unchanged) ---------------------------------------
__global__ __launch_bounds__(256) void ball_kernel(const float* __restrict__ pos,
                                                   const int* __restrict__ fps_idx,
                                                   int* __restrict__ nbr_cnt,
                                                   int* __restrict__ nbr_idx) {
    __shared__ float px[NP], py[NP], pz[NP];
    __shared__ float cd2[4][CAP];
    __shared__ int cix[4][CAP];
    const int tid = threadIdx.x;
    const int wv = tid >> 6, lane = tid & 63;
    const int b = blockIdx.x >> 4;
    const int grp = blockIdx.x & 15;
    const float* p = pos + (size_t)b * NP * 3;
    for (int e = tid; e < NP; e += 256) {
        px[e] = p[e * 3 + 0];
        py[e] = p[e * 3 + 1];
        pz[e] = p[e * 3 + 2];
    }
    __syncthreads();
    for (int i = 0; i < 16; ++i) {
        const int s = grp * 64 + i * 4 + wv;
        const int cen = b * NS + s;
        const int ci = fps_idx[cen];
        const float cx = px[ci], cy = py[ci], cz = pz[ci];
        int cnt = 0;
        for (int it = 0; it < NP / 64; ++it) {
            const int j = it * 64 + lane;
            float d2 = dist2e(cx, cy, cz, px[j], py[j], pz[j]);
            bool in = (d2 <= 0.01f);
            unsigned long long m = __ballot(in);
            if (in) {
                int slot = cnt + __popcll(m & ((1ull << lane) - 1ull));
                if (slot < CAP) { cd2[wv][slot] = d2; cix[wv][slot] = j; }
            }
            cnt += __popcll(m);
        }
        if (cnt > CAP) cnt = CAP;
        const int keep = cnt <= KN ? cnt : KN;
        if (lane == 0) nbr_cnt[cen] = keep;
        if (cnt <= KN) {
            if (lane < cnt) nbr_idx[(size_t)cen * KN + lane] = cix[wv][lane];
        } else {
            for (int e = lane; e < cnt; e += 64) {
                float d = cd2[wv][e];
                int id = cix[wv][e];
                int rank = 0;
                for (int q = 0; q < cnt; ++q) {
                    float dq = cd2[wv][q];
                    int iq = cix[wv][q];
                    rank += (dq < d || (dq == d && iq < id)) ? 1 : 0;
                }
                if (rank < KN) nbr_idx[(size_t)cen * KN + rank] = id;
            }
        }
    }
}

// ------- PointNetConv via MFMA 16x16x32 bf16: 8 centers/block, 4 waves ------
// Rows padded to 64 = 4 wave-private 16-row tiles (no inter-wave deps in
// layers). A(L1) gathered global->frag regs; W frags in regs; h1/h2 bf16 LDS
// with XOR swizzle idx^((row&7)<<3) on write AND read (G4 fix).
__global__ __launch_bounds__(256) void conv_kernel(const float* __restrict__ pos,
                                                   const float* __restrict__ x,
                                                   const int* __restrict__ fps_idx,
                                                   const int* __restrict__ nbr_cnt,
                                                   const int* __restrict__ nbr_idx,
                                                   const float* __restrict__ W1,
                                                   const float* __restrict__ b1,
                                                   const float* __restrict__ W2,
                                                   const float* __restrict__ b2,
                                                   const float* __restrict__ W3,
                                                   const float* __restrict__ b3,
                                                   float* __restrict__ out) {
    const int tid = threadIdx.x;
    const int lane = tid & 63;
    const int w = tid >> 6;       // wave = row-tile id (0..3)
    const int lg = lane >> 4;     // k-group (0..3)
    const int lr = lane & 15;     // row-in-tile (A) / col-in-tile (B,D)
    __shared__ short h1s[64 * 64];
    __shared__ short h2s[64 * 64];
    __shared__ float dpx[64], dpy[64], dpz[64];
    __shared__ int jr[64];
    __shared__ float omax[4][128];
    // ---- W fragments (bf16) into registers, once per block ----
    bf16x8 w1f[3][4], w2f[2][4], w3f[2][8];
#pragma unroll
    for (int kt = 0; kt < 3; ++kt)
#pragma unroll
        for (int ct = 0; ct < 4; ++ct) {
            bf16x8 f;
#pragma unroll
            for (int i = 0; i < 8; ++i) {
                int k = 32 * kt + 8 * lg + i;
                float v = (k < 67) ? W1[k * 64 + 16 * ct + lr] : 0.f;
                f[i] = f2bf(v);
            }
            w1f[kt][ct] = f;
        }
#pragma unroll
    for (int kt = 0; kt < 2; ++kt)
#pragma unroll
        for (int ct = 0; ct < 4; ++ct) {
            bf16x8 f;
#pragma unroll
            for (int i = 0; i < 8; ++i) {
                int k = 32 * kt + 8 * lg + i;
                f[i] = f2bf(W2[k * 64 + 16 * ct + lr]);
            }
            w2f[kt][ct] = f;
        }
#pragma unroll
    for (int kt = 0; kt < 2; ++kt)
#pragma unroll
        for (int ct = 0; ct < 8; ++ct) {
            bf16x8 f;
#pragma unroll
            for (int i = 0; i < 8; ++i) {
                int k = 32 * kt + 8 * lg + i;
                f[i] = f2bf(W3[k * 128 + 16 * ct + lr]);
            }
            w3f[kt][ct] = f;
        }
    float b1v[4], b2v[4], b3v[8];
#pragma unroll
    for (int ct = 0; ct < 4; ++ct) { b1v[ct] = b1[16 * ct + lr]; b2v[ct] = b2[16 * ct + lr]; }
#pragma unroll
    for (int ct = 0; ct < 8; ++ct) b3v[ct] = b3[16 * ct + lr];

    for (int cc = 0; cc < CPB; ++cc) {
        const int cen = blockIdx.x * CPB + cc;
        const int b = cen >> 10;  // NS=1024
        const int C = nbr_cnt[cen];
        if (tid < 64) {
            const float* pb = pos + (size_t)b * NP * 3;
            const int ci = fps_idx[cen];
            const float cx = pb[ci * 3 + 0], cy = pb[ci * 3 + 1], cz = pb[ci * 3 + 2];
            if (tid < C) {
                int j = nbr_idx[(size_t)cen * KN + tid];
                jr[tid] = b * NP + j;
                dpx[tid] = pb[j * 3 + 0] - cx;
                dpy[tid] = pb[j * 3 + 1] - cy;
                dpz[tid] = pb[j * 3 + 2] - cz;
            } else {
                jr[tid] = b * NP;  // valid dummy row; masked at aggregation
                dpx[tid] = 0.f; dpy[tid] = 0.f; dpz[tid] = 0.f;
            }
        }
        __syncthreads();
        const int arow = 16 * w + lr;              // A-frag row (this lane)
        // ---- layer 1: A from global x + dp tail, all in regs ----
        bf16x8 a0, a1, a2;
        {
            const float* xr = x + (size_t)jr[arow] * FIN + 8 * lg;
            float4 v0 = *(const float4*)(xr + 0);
            float4 v1 = *(const float4*)(xr + 4);
            float4 v2 = *(const float4*)(xr + 32);
            float4 v3 = *(const float4*)(xr + 36);
            a0[0] = f2bf(v0.x); a0[1] = f2bf(v0.y); a0[2] = f2bf(v0.z); a0[3] = f2bf(v0.w);
            a0[4] = f2bf(v1.x); a0[5] = f2bf(v1.y); a0[6] = f2bf(v1.z); a0[7] = f2bf(v1.w);
            a1[0] = f2bf(v2.x); a1[1] = f2bf(v2.y); a1[2] = f2bf(v2.z); a1[3] = f2bf(v2.w);
            a1[4] = f2bf(v3.x); a1[5] = f2bf(v3.y); a1[6] = f2bf(v3.z); a1[7] = f2bf(v3.w);
            float d0 = (lg == 0) ? dpx[arow] : 0.f;
            float d1 = (lg == 0) ? dpy[arow] : 0.f;
            float d2 = (lg == 0) ? dpz[arow] : 0.f;
            a2[0] = f2bf(d0); a2[1] = f2bf(d1); a2[2] = f2bf(d2);
            a2[3] = 0; a2[4] = 0; a2[5] = 0; a2[6] = 0; a2[7] = 0;
        }
        {
            f32x4 acc[4];
#pragma unroll
            for (int ct = 0; ct < 4; ++ct) {
                acc[ct] = (f32x4){b1v[ct], b1v[ct], b1v[ct], b1v[ct]};
                acc[ct] = __builtin_amdgcn_mfma_f32_16x16x32_bf16(a0, w1f[0][ct], acc[ct], 0, 0, 0);
                acc[ct] = __builtin_amdgcn_mfma_f32_16x16x32_bf16(a1, w1f[1][ct], acc[ct], 0, 0, 0);
                acc[ct] = __builtin_amdgcn_mfma_f32_16x16x32_bf16(a2, w1f[2][ct], acc[ct], 0, 0, 0);
            }
            // relu -> h1 (bf16, swizzled)
#pragma unroll
            for (int ct = 0; ct < 4; ++ct)
#pragma unroll
                for (int r = 0; r < 4; ++r) {
                    int rw = 16 * w + 4 * lg + r;        // D row = (lane>>4)*4+reg
                    int idx = rw * 64 + 16 * ct + lr;    // D col = lane&15
                    h1s[idx ^ ((rw & 7) << 3)] = f2bf(fmaxf(acc[ct][r], 0.f));
                }
        }
        // ---- layer 2 ----
        bf16x8 ha0 = *(bf16x8*)&h1s[(arow * 64 + 0  + 8 * lg) ^ ((arow & 7) << 3)];
        bf16x8 ha1 = *(bf16x8*)&h1s[(arow * 64 + 32 + 8 * lg) ^ ((arow & 7) << 3)];
        {
            f32x4 acc[4];
#pragma unroll
            for (int ct = 0; ct < 4; ++ct) {
                acc[ct] = (f32x4){b2v[ct], b2v[ct], b2v[ct], b2v[ct]};
                acc[ct] = __builtin_amdgcn_mfma_f32_16x16x32_bf16(ha0, w2f[0][ct], acc[ct], 0, 0, 0);
                acc[ct] = __builtin_amdgcn_mfma_f32_16x16x32_bf16(ha1, w2f[1][ct], acc[ct], 0, 0, 0);
            }
#pragma unroll
            for (int ct = 0; ct < 4; ++ct)
#pragma unroll
                for (int r = 0; r < 4; ++r) {
                    int rw = 16 * w + 4 * lg + r;
                    int idx = rw * 64 + 16 * ct + lr;
                    h2s[idx ^ ((rw & 7) << 3)] = f2bf(fmaxf(acc[ct][r], 0.f));
                }
        }
        // ---- layer 3 + masked max aggregation ----
        bf16x8 hb0 = *(bf16x8*)&h2s[(arow * 64 + 0  + 8 * lg) ^ ((arow & 7) << 3)];
        bf16x8 hb1 = *(bf16x8*)&h2s[(arow * 64 + 32 + 8 * lg) ^ ((arow & 7) << 3)];
        {
            f32x4 acc3[8];
#pragma unroll
            for (int ct = 0; ct < 8; ++ct) {
                acc3[ct] = (f32x4){b3v[ct], b3v[ct], b3v[ct], b3v[ct]};
                acc3[ct] = __builtin_amdgcn_mfma_f32_16x16x32_bf16(hb0, w3f[0][ct], acc3[ct], 0, 0, 0);
                acc3[ct] = __builtin_amdgcn_mfma_f32_16x16x32_bf16(hb1, w3f[1][ct], acc3[ct], 0, 0, 0);
            }
#pragma unroll
            for (int ct = 0; ct < 8; ++ct) {
                float m = -INFINITY;
#pragma unroll
                for (int r = 0; r < 4; ++r) {
                    int rg = 16 * w + 4 * lg + r;
                    float v = fmaxf(acc3[ct][r], 0.f);   // relu
                    m = (rg < C && v > m) ? v : m;       // mask padded rows
                }
                m = fmaxf(m, __shfl_xor(m, 16, 64));
                m = fmaxf(m, __shfl_xor(m, 32, 64));
                if (lg == 0) omax[w][16 * ct + lr] = m;
            }
        }
        __syncthreads();
        if (tid < 128) {
            float m = fmaxf(fmaxf(omax[0][tid], omax[1][tid]),
                            fmaxf(omax[2][tid], omax[3][tid]));
            out[(size_t)cen * 128 + tid] = m;
        }
        __syncthreads();  // protect jr/dp/omax reuse next center
    }
}

extern "C" void kernel_launch(void* const* d_in, const int* in_sizes, int n_in,
                              void* d_out, int out_size, void* d_ws, size_t ws_size,
                              hipStream_t stream) {
    const float* x   = (const float*)d_in[0];
    const float* pos = (const float*)d_in[1];
    const float* W1  = (const float*)d_in[3];
    const float* b1  = (const float*)d_in[4];
    const float* W2  = (const float*)d_in[5];
    const float* b2  = (const float*)d_in[6];
    const float* W3  = (const float*)d_in[7];
    const float* b3  = (const float*)d_in[8];
    float* out = (float*)d_out;
    char* ws = (char*)d_ws;
    int* fps_idx = (int*)(ws);                     // 16384 * 4 B
    int* nbr_cnt = (int*)(ws + 16384 * 4);         // 16384 * 4 B
    int* nbr_idx = (int*)(ws + 16384 * 8);         // 16384 * 64 * 4 B = 4 MB
    float* out_feat  = out;                         // [16384][128]
    float* out_pos   = out + (size_t)16384 * 128;   // [16384][3]
    float* out_batch = out + (size_t)16384 * 131;   // [16384]
    fps_kernel<<<NB, 256, 0, stream>>>(pos, fps_idx, out_pos, out_batch);
    ball_kernel<<<NB * 16, 256, 0, stream>>>(pos, fps_idx, nbr_cnt, nbr_idx);
    conv_kernel<<<NB * NS / CPB, 256, 0, stream>>>(pos, x, fps_idx, nbr_cnt,
                                                   nbr_idx, W1, b1, W2, b2,
                                                   W3, b3, out_feat);
}

// Round 11
// 960.741 us; speedup vs baseline: 2.1958x; 1.1874x over previous
//
#include <hip/hip_runtime.h>
#include <hip/hip_bf16.h>
#include <math.h>

// PointNet++ SAModule: FPS -> ball query -> PointNetConv(MLP, max-agg)
// B=16, N=4096, S=1024, K=64, r=0.1, MLP 67->64->64->128.
// R11: single fused producer/consumer kernel, grid=256 blocks (=CUs).
// Blocks 0-15: R9 FPS (unchanged math), publish center coords every 64 steps
// (agent atomics + release progress). Blocks 16-255: consumers; per-wave ball
// (pos from L2), R10 MFMA conv per 4-center chunk, acquire-spin on progress.
// Ball+conv (~290us machine work) hides behind the 850us FPS chain.

#define NB 16
#define NP 4096
#define FIN 64
#define NS 1024
#define KN 64
#define CAP 128
#define NCONS 240
#define NCHUNK 4096

typedef __attribute__((ext_vector_type(8))) short bf16x8;
typedef __attribute__((ext_vector_type(4))) float f32x4;

__device__ __forceinline__ float dist2e(float ax, float ay, float az,
                                        float bx, float by, float bz) {
    float dx = __fsub_rn(ax, bx);
    float dy = __fsub_rn(ay, by);
    float dz = __fsub_rn(az, bz);
    return __fadd_rn(__fadd_rn(__fmul_rn(dx, dx), __fmul_rn(dy, dy)),
                     __fmul_rn(dz, dz));
}

__device__ __forceinline__ short f2bf(float f) {  // RNE fp32 -> bf16 bits
    unsigned u = __float_as_uint(f);
    unsigned r = (u + 0x7FFFu + ((u >> 16) & 1u)) >> 16;
    return (short)r;
}

#define DPP_KEY_MAX(k, CTRL)                                                   \
    do {                                                                       \
        int _lo = (int)(unsigned)((k) & 0xFFFFFFFFull);                        \
        int _hi = (int)(unsigned)((k) >> 32);                                  \
        int _plo = __builtin_amdgcn_update_dpp(_lo, _lo, CTRL, 0xF, 0xF, false);\
        int _phi = __builtin_amdgcn_update_dpp(_hi, _hi, CTRL, 0xF, 0xF, false);\
        unsigned long long _nk =                                               \
            ((unsigned long long)(unsigned)_phi << 32) | (unsigned)_plo;       \
        if (_nk > (k)) (k) = _nk;                                              \
    } while (0)

#define SMEM_BYTES 27648

__global__ __launch_bounds__(256) void fused_kernel(
        const float* __restrict__ pos, const float* __restrict__ x,
        const float* __restrict__ W1, const float* __restrict__ b1,
        const float* __restrict__ W2, const float* __restrict__ b2,
        const float* __restrict__ W3, const float* __restrict__ b3,
        float* __restrict__ out_feat, float* __restrict__ out_pos,
        float* __restrict__ out_batch, float* __restrict__ histg,
        int* __restrict__ progress) {
    __shared__ __align__(16) char smem[SMEM_BYTES];
    const int tid = threadIdx.x;
    const int lane = tid & 63;
    const int wv = tid >> 6;

    if (blockIdx.x < NB) {
        // =================== FPS producer (R9 math, verbatim) ===============
        const int b = blockIdx.x;
        float4* hist = (float4*)smem;                       // [1024] 16KB
        float (*bc)[4][8] = (float(*)[4][8])(smem + 16384); // [2][4][8]
        const float* p = pos + (size_t)b * NP * 3;
        float lx[16], ly[16], lz[16], md[16];
#pragma unroll
        for (int i = 0; i < 16; ++i) {
            int j = tid + (i << 8);
            lx[i] = p[j * 3 + 0];
            ly[i] = p[j * 3 + 1];
            lz[i] = p[j * 3 + 2];
            md[i] = INFINITY;
        }
        const float c0x = p[0], c0y = p[1], c0z = p[2];
        float cx = c0x, cy = c0y, cz = c0z;
        if (tid == 0) hist[0] = make_float4(0.f, c0x, c0y, c0z);
        for (int s = 1; s < NS; ++s) {
            float bv = -1.0f;
            int bi = 0;
            float wx = 0.f, wy = 0.f, wz = 0.f;
#pragma unroll
            for (int i = 0; i < 16; ++i) {
                float d = dist2e(lx[i], ly[i], lz[i], cx, cy, cz);
                float m = md[i];
                m = d < m ? d : m;   // jnp.minimum (exact)
                md[i] = m;
                bool take = (m > bv);
                bv = take ? m : bv;
                bi = take ? (tid + (i << 8)) : bi;
                wx = take ? lx[i] : wx;
                wy = take ? ly[i] : wy;
                wz = take ? lz[i] : wz;
            }
            unsigned long long key =
                ((unsigned long long)__float_as_uint(bv) << 32) |
                (unsigned)(~(unsigned)bi);
            const unsigned long long my = key;
            DPP_KEY_MAX(key, 0x111);
            DPP_KEY_MAX(key, 0x112);
            DPP_KEY_MAX(key, 0x114);
            DPP_KEY_MAX(key, 0x118);
            DPP_KEY_MAX(key, 0x142);
            DPP_KEY_MAX(key, 0x143);
            const unsigned kwlo = (unsigned)__builtin_amdgcn_readlane(
                (int)(unsigned)(key & 0xFFFFFFFFull), 63);
            const unsigned kwhi = (unsigned)__builtin_amdgcn_readlane(
                (int)(unsigned)(key >> 32), 63);
            const unsigned long long kw =
                ((unsigned long long)kwhi << 32) | kwlo;
            const int buf = s & 1;
            if (my == kw) {
                bc[buf][wv][0] = __uint_as_float(kwlo);
                bc[buf][wv][1] = __uint_as_float(kwhi);
                bc[buf][wv][2] = wx;
                bc[buf][wv][3] = wy;
                bc[buf][wv][4] = wz;
            }
            __syncthreads();
            if ((s & 63) == 0) {   // publish centers [s-64, s)
                const int base = s - 64;
                if (tid < 192) {
                    int cc = tid / 3, comp = tid % 3;
                    float4 h = hist[base + cc];
                    float v = comp == 0 ? h.y : (comp == 1 ? h.z : h.w);
                    __hip_atomic_store(
                        (unsigned*)&histg[((size_t)(b * NS + base + cc)) * 3 + comp],
                        __float_as_uint(v), __ATOMIC_RELAXED,
                        __HIP_MEMORY_SCOPE_AGENT);
                }
                __threadfence();
                __syncthreads();
                if (tid == 0)
                    __hip_atomic_store(&progress[b], s, __ATOMIC_RELEASE,
                                       __HIP_MEMORY_SCOPE_AGENT);
            }
            unsigned long long bk;
            float bx, by, bz;
            {
                float4 e = *(const float4*)&bc[buf][0][0];
                bk = ((unsigned long long)__float_as_uint(e.y) << 32) |
                     __float_as_uint(e.x);
                bx = e.z; by = e.w; bz = bc[buf][0][4];
            }
#pragma unroll
            for (int w = 1; w < 4; ++w) {
                float4 e = *(const float4*)&bc[buf][w][0];
                unsigned long long k2 =
                    ((unsigned long long)__float_as_uint(e.y) << 32) |
                    __float_as_uint(e.x);
                float z2 = bc[buf][w][4];
                bool take = (k2 > bk);
                bk = take ? k2 : bk;
                bx = take ? e.z : bx;
                by = take ? e.w : by;
                bz = take ? z2 : bz;
            }
            const int cur = (int)(~(unsigned)(bk & 0xFFFFFFFFull));
            cx = bx; cy = by; cz = bz;
            if (tid == 0)
                hist[s] = make_float4(__int_as_float(cur), bx, by, bz);
        }
        __syncthreads();
        // final publish [960,1024) + output drain
        if (tid < 192) {
            int cc = tid / 3, comp = tid % 3;
            float4 h = hist[960 + cc];
            float v = comp == 0 ? h.y : (comp == 1 ? h.z : h.w);
            __hip_atomic_store(
                (unsigned*)&histg[((size_t)(b * NS + 960 + cc)) * 3 + comp],
                __float_as_uint(v), __ATOMIC_RELAXED, __HIP_MEMORY_SCOPE_AGENT);
        }
        __threadfence();
        __syncthreads();
        if (tid == 0)
            __hip_atomic_store(&progress[b], NS, __ATOMIC_RELEASE,
                               __HIP_MEMORY_SCOPE_AGENT);
        for (int s = tid; s < NS; s += 256) {
            float4 e = hist[s];
            out_pos[(size_t)(b * NS + s) * 3 + 0] = e.y;
            out_pos[(size_t)(b * NS + s) * 3 + 1] = e.z;
            out_pos[(size_t)(b * NS + s) * 3 + 2] = e.w;
            out_batch[b * NS + s] = (float)b;
        }
        return;
    }

    // ======================= consumer: ball + MFMA conv ======================
    const int w = blockIdx.x - NB;  // 0..239
    short* h1s = (short*)smem;                      // 8KB
    short* h2s = (short*)(smem + 8192);             // 8KB
    float* cd2 = (float*)(smem + 16384);            // [4][CAP]
    int*   cix = (int*)(smem + 18432);              // [4][CAP]
    float* dpxA = (float*)(smem + 20480);           // [4][64]
    float* dpyA = (float*)(smem + 21504);
    float* dpzA = (float*)(smem + 22528);
    int*   jA   = (int*)(smem + 23552);             // [4][64]
    float* omax = (float*)(smem + 24576);           // [4][128]
    int*   keepW = (int*)(smem + 26624);            // [4]
    const int lg = lane >> 4;
    const int lr = lane & 15;
    // ---- W fragments (bf16) into registers, once per block (R10) ----
    bf16x8 w1f[3][4], w2f[2][4], w3f[2][8];
#pragma unroll
    for (int kt = 0; kt < 3; ++kt)
#pragma unroll
        for (int ct = 0; ct < 4; ++ct) {
            bf16x8 f;
#pragma unroll
            for (int i = 0; i < 8; ++i) {
                int k = 32 * kt + 8 * lg + i;
                float v = (k < 67) ? W1[k * 64 + 16 * ct + lr] : 0.f;
                f[i] = f2bf(v);
            }
            w1f[kt][ct] = f;
        }
#pragma unroll
    for (int kt = 0; kt < 2; ++kt)
#pragma unroll
        for (int ct = 0; ct < 4; ++ct) {
            bf16x8 f;
#pragma unroll
            for (int i = 0; i < 8; ++i) {
                int k = 32 * kt + 8 * lg + i;
                f[i] = f2bf(W2[k * 64 + 16 * ct + lr]);
            }
            w2f[kt][ct] = f;
        }
#pragma unroll
    for (int kt = 0; kt < 2; ++kt)
#pragma unroll
        for (int ct = 0; ct < 8; ++ct) {
            bf16x8 f;
#pragma unroll
            for (int i = 0; i < 8; ++i) {
                int k = 32 * kt + 8 * lg + i;
                f[i] = f2bf(W3[k * 128 + 16 * ct + lr]);
            }
            w3f[kt][ct] = f;
        }
    float b1v[4], b2v[4], b3v[8];
#pragma unroll
    for (int ct = 0; ct < 4; ++ct) {
        b1v[ct] = b1[16 * ct + lr];
        b2v[ct] = b2[16 * ct + lr];
    }
#pragma unroll
    for (int ct = 0; ct < 8; ++ct) b3v[ct] = b3[16 * ct + lr];

    for (int c = w; c < NCHUNK; c += NCONS) {
        const int s = c >> 2;
        const int bq = (c & 3) << 2;
        // ---- per-wave: spin until my cloud's center s is published ----
        const int bw = bq + wv;
        while (__hip_atomic_load(&progress[bw], __ATOMIC_ACQUIRE,
                                 __HIP_MEMORY_SCOPE_AGENT) <= s) {
            __builtin_amdgcn_s_sleep(2);
        }
        const size_t ho = ((size_t)(bw * NS + s)) * 3;
        const float ccx = __uint_as_float(__hip_atomic_load(
            (const unsigned*)&histg[ho + 0], __ATOMIC_RELAXED,
            __HIP_MEMORY_SCOPE_AGENT));
        const float ccy = __uint_as_float(__hip_atomic_load(
            (const unsigned*)&histg[ho + 1], __ATOMIC_RELAXED,
            __HIP_MEMORY_SCOPE_AGENT));
        const float ccz = __uint_as_float(__hip_atomic_load(
            (const unsigned*)&histg[ho + 2], __ATOMIC_RELAXED,
            __HIP_MEMORY_SCOPE_AGENT));
        // ---- per-wave ball query (64 pts/lane, j ascending it-major) ----
        int cnt = 0;
        const float* pcloud = pos + (size_t)bw * NP * 3;
        for (int it = 0; it < 64; ++it) {
            const int j = it * 64 + lane;
            const float* pp = pcloud + (size_t)j * 3;
            float d2 = dist2e(ccx, ccy, ccz, pp[0], pp[1], pp[2]);
            bool in = (d2 <= 0.01f);  // f32(0.1*0.1)
            unsigned long long m = __ballot(in);
            if (in) {
                int slot = cnt + __popcll(m & ((1ull << lane) - 1ull));
                if (slot < CAP) {
                    cd2[wv * CAP + slot] = d2;
                    cix[wv * CAP + slot] = j;
                }
            }
            cnt += __popcll(m);
        }
        if (cnt > CAP) cnt = CAP;
        const int keep = cnt <= KN ? cnt : KN;
        if (lane == 0) keepW[wv] = keep;
        // rows -> jA (padded rows = 0)
        jA[wv * 64 + lane] = 0;
        if (cnt <= KN) {
            if (lane < keep) jA[wv * 64 + lane] = cix[wv * CAP + lane];
        } else {
            // exact K-nearest: rank by (d2, idx) lexicographic (top_k order)
            for (int e = lane; e < cnt; e += 64) {
                float d = cd2[wv * CAP + e];
                int id = cix[wv * CAP + e];
                int rank = 0;
                for (int q = 0; q < cnt; ++q) {
                    float dq = cd2[wv * CAP + q];
                    int iq = cix[wv * CAP + q];
                    rank += (dq < d || (dq == d && iq < id)) ? 1 : 0;
                }
                if (rank < KN) jA[wv * 64 + rank] = id;
            }
        }
        {
            int j = jA[wv * 64 + lane];
            const float* pp = pcloud + (size_t)j * 3;
            bool valid = lane < keep;
            dpxA[wv * 64 + lane] = valid ? (pp[0] - ccx) : 0.f;
            dpyA[wv * 64 + lane] = valid ? (pp[1] - ccy) : 0.f;
            dpzA[wv * 64 + lane] = valid ? (pp[2] - ccz) : 0.f;
        }
        __syncthreads();
        // ---- conv for the 4 centers (R10 MFMA path) ----
        for (int cc = 0; cc < 4; ++cc) {
            const int C = keepW[cc];
            const int cen = (bq + cc) * NS + s;
            const int arow = 16 * wv + lr;
            bf16x8 a0, a1, a2;
            {
                const int jrow = (bq + cc) * NP + jA[cc * 64 + arow];
                const float* xr = x + (size_t)jrow * FIN + 8 * lg;
                float4 v0 = *(const float4*)(xr + 0);
                float4 v1 = *(const float4*)(xr + 4);
                float4 v2 = *(const float4*)(xr + 32);
                float4 v3 = *(const float4*)(xr + 36);
                a0[0] = f2bf(v0.x); a0[1] = f2bf(v0.y); a0[2] = f2bf(v0.z); a0[3] = f2bf(v0.w);
                a0[4] = f2bf(v1.x); a0[5] = f2bf(v1.y); a0[6] = f2bf(v1.z); a0[7] = f2bf(v1.w);
                a1[0] = f2bf(v2.x); a1[1] = f2bf(v2.y); a1[2] = f2bf(v2.z); a1[3] = f2bf(v2.w);
                a1[4] = f2bf(v3.x); a1[5] = f2bf(v3.y); a1[6] = f2bf(v3.z); a1[7] = f2bf(v3.w);
                float d0 = (lg == 0) ? dpxA[cc * 64 + arow] : 0.f;
                float d1 = (lg == 0) ? dpyA[cc * 64 + arow] : 0.f;
                float d2v = (lg == 0) ? dpzA[cc * 64 + arow] : 0.f;
                a2[0] = f2bf(d0); a2[1] = f2bf(d1); a2[2] = f2bf(d2v);
                a2[3] = 0; a2[4] = 0; a2[5] = 0; a2[6] = 0; a2[7] = 0;
            }
            {
                f32x4 acc[4];
#pragma unroll
                for (int ct = 0; ct < 4; ++ct) {
                    acc[ct] = (f32x4){b1v[ct], b1v[ct], b1v[ct], b1v[ct]};
                    acc[ct] = __builtin_amdgcn_mfma_f32_16x16x32_bf16(a0, w1f[0][ct], acc[ct], 0, 0, 0);
                    acc[ct] = __builtin_amdgcn_mfma_f32_16x16x32_bf16(a1, w1f[1][ct], acc[ct], 0, 0, 0);
                    acc[ct] = __builtin_amdgcn_mfma_f32_16x16x32_bf16(a2, w1f[2][ct], acc[ct], 0, 0, 0);
                }
#pragma unroll
                for (int ct = 0; ct < 4; ++ct)
#pragma unroll
                    for (int r = 0; r < 4; ++r) {
                        int rw = 16 * wv + 4 * lg + r;
                        int idx = rw * 64 + 16 * ct + lr;
                        h1s[idx ^ ((rw & 7) << 3)] = f2bf(fmaxf(acc[ct][r], 0.f));
                    }
            }
            bf16x8 ha0 = *(bf16x8*)&h1s[(arow * 64 + 0  + 8 * lg) ^ ((arow & 7) << 3)];
            bf16x8 ha1 = *(bf16x8*)&h1s[(arow * 64 + 32 + 8 * lg) ^ ((arow & 7) << 3)];
            {
                f32x4 acc[4];
#pragma unroll
                for (int ct = 0; ct < 4; ++ct) {
                    acc[ct] = (f32x4){b2v[ct], b2v[ct], b2v[ct], b2v[ct]};
                    acc[ct] = __builtin_amdgcn_mfma_f32_16x16x32_bf16(ha0, w2f[0][ct], acc[ct], 0, 0, 0);
                    acc[ct] = __builtin_amdgcn_mfma_f32_16x16x32_bf16(ha1, w2f[1][ct], acc[ct], 0, 0, 0);
                }
#pragma unroll
                for (int ct = 0; ct < 4; ++ct)
#pragma unroll
                    for (int r = 0; r < 4; ++r) {
                        int rw = 16 * wv + 4 * lg + r;
                        int idx = rw * 64 + 16 * ct + lr;
                        h2s[idx ^ ((rw & 7) << 3)] = f2bf(fmaxf(acc[ct][r], 0.f));
                    }
            }
            bf16x8 hb0 = *(bf16x8*)&h2s[(arow * 64 + 0  + 8 * lg) ^ ((arow & 7) << 3)];
            bf16x8 hb1 = *(bf16x8*)&h2s[(arow * 64 + 32 + 8 * lg) ^ ((arow & 7) << 3)];
            {
                f32x4 acc3[8];
#pragma unroll
                for (int ct = 0; ct < 8; ++ct) {
                    acc3[ct] = (f32x4){b3v[ct], b3v[ct], b3v[ct], b3v[ct]};
                    acc3[ct] = __builtin_amdgcn_mfma_f32_16x16x32_bf16(hb0, w3f[0][ct], acc3[ct], 0, 0, 0);
                    acc3[ct] = __builtin_amdgcn_mfma_f32_16x16x32_bf16(hb1, w3f[1][ct], acc3[ct], 0, 0, 0);
                }
#pragma unroll
                for (int ct = 0; ct < 8; ++ct) {
                    float m = -INFINITY;
#pragma unroll
                    for (int r = 0; r < 4; ++r) {
                        int rg = 16 * wv + 4 * lg + r;
                        float v = fmaxf(acc3[ct][r], 0.f);
                        m = (rg < C && v > m) ? v : m;
                    }
                    m = fmaxf(m, __shfl_xor(m, 16, 64));
                    m = fmaxf(m, __shfl_xor(m, 32, 64));
                    if (lg == 0) omax[wv * 128 + 16 * ct + lr] = m;
                }
            }
            __syncthreads();
            if (tid < 128) {
                float m = fmaxf(fmaxf(omax[0 * 128 + tid], omax[1 * 128 + tid]),
                                fmaxf(omax[2 * 128 + tid], omax[3 * 128 + tid]));
                out_feat[(size_t)cen * 128 + tid] = m;
            }
            __syncthreads();
        }
    }
}

extern "C" void kernel_launch(void* const* d_in, const int* in_sizes, int n_in,
                              void* d_out, int out_size, void* d_ws, size_t ws_size,
                              hipStream_t stream) {
    const float* x   = (const float*)d_in[0];
    const float* pos = (const float*)d_in[1];
    const float* W1  = (const float*)d_in[3];
    const float* b1  = (const float*)d_in[4];
    const float* W2  = (const float*)d_in[5];
    const float* b2  = (const float*)d_in[6];
    const float* W3  = (const float*)d_in[7];
    const float* b3  = (const float*)d_in[8];
    float* out = (float*)d_out;
    char* ws = (char*)d_ws;
    int*   progress = (int*)ws;                    // 16 ints (zeroed below)
    float* histg    = (float*)(ws + 256);          // [16][1024][3] = 192KB
    float* out_feat  = out;                        // [16384][128]
    float* out_pos   = out + (size_t)16384 * 128;  // [16384][3]
    float* out_batch = out + (size_t)16384 * 131;  // [16384]
    hipMemsetAsync(ws, 0, 256, stream);
    fused_kernel<<<256, 256, 0, stream>>>(pos, x, W1, b1, W2, b2, W3, b3,
                                          out_feat, out_pos, out_batch,
                                          histg, progress);
}

// Round 12
// 914.193 us; speedup vs baseline: 2.3076x; 1.0509x over previous
//
#include <hip/hip_runtime.h>
#include <hip/hip_bf16.h>
#include <math.h>

// PointNet++ SAModule: FPS -> ball query -> PointNetConv(MLP, max-agg)
// B=16, N=4096, S=1024, K=64, r=0.1, MLP 67->64->64->128.
// R12: (a) producer position arrays PINNED in VGPRs (launch_bounds(256,1) +
// inline-asm "+v" defs) -- R9/R11's VGPR=68 proved lx/ly/lz were re-loaded
// from memory every step, the hidden ~1000cy/step cost; (b) progress[] padded
// to 128B/cloud + s_sleep(16) to kill the single-cache-line spin storm;
// (c) redundant __threadfence removed (barrier vmcnt-drain + agent-release
// store is sufficient). Math/order identical everywhere -> same absmax.

#define NB 16
#define NP 4096
#define FIN 64
#define NS 1024
#define KN 64
#define CAP 128
#define NCONS 240
#define NCHUNK 4096

typedef __attribute__((ext_vector_type(8))) short bf16x8;
typedef __attribute__((ext_vector_type(4))) float f32x4;

__device__ __forceinline__ float dist2e(float ax, float ay, float az,
                                        float bx, float by, float bz) {
    float dx = __fsub_rn(ax, bx);
    float dy = __fsub_rn(ay, by);
    float dz = __fsub_rn(az, bz);
    return __fadd_rn(__fadd_rn(__fmul_rn(dx, dx), __fmul_rn(dy, dy)),
                     __fmul_rn(dz, dz));
}

__device__ __forceinline__ short f2bf(float f) {  // RNE fp32 -> bf16 bits
    unsigned u = __float_as_uint(f);
    unsigned r = (u + 0x7FFFu + ((u >> 16) & 1u)) >> 16;
    return (short)r;
}

#define DPP_KEY_MAX(k, CTRL)                                                   \
    do {                                                                       \
        int _lo = (int)(unsigned)((k) & 0xFFFFFFFFull);                        \
        int _hi = (int)(unsigned)((k) >> 32);                                  \
        int _plo = __builtin_amdgcn_update_dpp(_lo, _lo, CTRL, 0xF, 0xF, false);\
        int _phi = __builtin_amdgcn_update_dpp(_hi, _hi, CTRL, 0xF, 0xF, false);\
        unsigned long long _nk =                                               \
            ((unsigned long long)(unsigned)_phi << 32) | (unsigned)_plo;       \
        if (_nk > (k)) (k) = _nk;                                              \
    } while (0)

#define SMEM_BYTES 27648

__global__ __launch_bounds__(256, 1) void fused_kernel(
        const float* __restrict__ pos, const float* __restrict__ x,
        const float* __restrict__ W1, const float* __restrict__ b1,
        const float* __restrict__ W2, const float* __restrict__ b2,
        const float* __restrict__ W3, const float* __restrict__ b3,
        float* __restrict__ out_feat, float* __restrict__ out_pos,
        float* __restrict__ out_batch, float* __restrict__ histg,
        int* __restrict__ progress) {
    __shared__ __align__(16) char smem[SMEM_BYTES];
    const int tid = threadIdx.x;
    const int lane = tid & 63;
    const int wv = tid >> 6;

    if (blockIdx.x < NB) {
        // =================== FPS producer (R9 math) =========================
        const int b = blockIdx.x;
        float4* hist = (float4*)smem;                       // [1024] 16KB
        float (*bc)[4][8] = (float(*)[4][8])(smem + 16384); // [2][4][8]
        const float* p = pos + (size_t)b * NP * 3;
        float lx[16], ly[16], lz[16], md[16];
#pragma unroll
        for (int i = 0; i < 16; ++i) {
            int j = tid + (i << 8);
            lx[i] = p[j * 3 + 0];
            ly[i] = p[j * 3 + 1];
            lz[i] = p[j * 3 + 2];
            md[i] = INFINITY;
        }
        // PIN the 48 position values in VGPRs: asm-defined -> the compiler
        // cannot re-materialize the global loads inside the step loop.
#pragma unroll
        for (int i = 0; i < 16; ++i) {
            asm volatile("" : "+v"(lx[i]), "+v"(ly[i]), "+v"(lz[i]));
        }
        const float c0x = p[0], c0y = p[1], c0z = p[2];
        float cx = c0x, cy = c0y, cz = c0z;
        if (tid == 0) hist[0] = make_float4(0.f, c0x, c0y, c0z);
        for (int s = 1; s < NS; ++s) {
            float bv = -1.0f;
            int bi = 0;
            float wx = 0.f, wy = 0.f, wz = 0.f;
#pragma unroll
            for (int i = 0; i < 16; ++i) {
                float d = dist2e(lx[i], ly[i], lz[i], cx, cy, cz);
                float m = md[i];
                m = d < m ? d : m;   // jnp.minimum (exact)
                md[i] = m;
                bool take = (m > bv);
                bv = take ? m : bv;
                bi = take ? (tid + (i << 8)) : bi;
                wx = take ? lx[i] : wx;
                wy = take ? ly[i] : wy;
                wz = take ? lz[i] : wz;
            }
            unsigned long long key =
                ((unsigned long long)__float_as_uint(bv) << 32) |
                (unsigned)(~(unsigned)bi);
            const unsigned long long my = key;
            DPP_KEY_MAX(key, 0x111);
            DPP_KEY_MAX(key, 0x112);
            DPP_KEY_MAX(key, 0x114);
            DPP_KEY_MAX(key, 0x118);
            DPP_KEY_MAX(key, 0x142);
            DPP_KEY_MAX(key, 0x143);
            const unsigned kwlo = (unsigned)__builtin_amdgcn_readlane(
                (int)(unsigned)(key & 0xFFFFFFFFull), 63);
            const unsigned kwhi = (unsigned)__builtin_amdgcn_readlane(
                (int)(unsigned)(key >> 32), 63);
            const unsigned long long kw =
                ((unsigned long long)kwhi << 32) | kwlo;
            const int buf = s & 1;
            if (my == kw) {
                bc[buf][wv][0] = __uint_as_float(kwlo);
                bc[buf][wv][1] = __uint_as_float(kwhi);
                bc[buf][wv][2] = wx;
                bc[buf][wv][3] = wy;
                bc[buf][wv][4] = wz;
            }
            __syncthreads();
            if ((s & 63) == 0) {   // publish centers [s-64, s)
                const int base = s - 64;
                if (tid < 192) {
                    int cc = tid / 3, comp = tid % 3;
                    float4 h = hist[base + cc];
                    float v = comp == 0 ? h.y : (comp == 1 ? h.z : h.w);
                    __hip_atomic_store(
                        (unsigned*)&histg[((size_t)(b * NS + base + cc)) * 3 + comp],
                        __float_as_uint(v), __ATOMIC_RELAXED,
                        __HIP_MEMORY_SCOPE_AGENT);
                }
                __syncthreads();   // vmcnt(0) drain -> stores agent-visible
                if (tid == 0)
                    __hip_atomic_store(&progress[b << 5], s, __ATOMIC_RELEASE,
                                       __HIP_MEMORY_SCOPE_AGENT);
            }
            unsigned long long bk;
            float bx, by, bz;
            {
                float4 e = *(const float4*)&bc[buf][0][0];
                bk = ((unsigned long long)__float_as_uint(e.y) << 32) |
                     __float_as_uint(e.x);
                bx = e.z; by = e.w; bz = bc[buf][0][4];
            }
#pragma unroll
            for (int w = 1; w < 4; ++w) {
                float4 e = *(const float4*)&bc[buf][w][0];
                unsigned long long k2 =
                    ((unsigned long long)__float_as_uint(e.y) << 32) |
                    __float_as_uint(e.x);
                float z2 = bc[buf][w][4];
                bool take = (k2 > bk);
                bk = take ? k2 : bk;
                bx = take ? e.z : bx;
                by = take ? e.w : by;
                bz = take ? z2 : bz;
            }
            const int cur = (int)(~(unsigned)(bk & 0xFFFFFFFFull));
            cx = bx; cy = by; cz = bz;
            if (tid == 0)
                hist[s] = make_float4(__int_as_float(cur), bx, by, bz);
        }
        __syncthreads();
        // final publish [960,1024) + output drain
        if (tid < 192) {
            int cc = tid / 3, comp = tid % 3;
            float4 h = hist[960 + cc];
            float v = comp == 0 ? h.y : (comp == 1 ? h.z : h.w);
            __hip_atomic_store(
                (unsigned*)&histg[((size_t)(b * NS + 960 + cc)) * 3 + comp],
                __float_as_uint(v), __ATOMIC_RELAXED, __HIP_MEMORY_SCOPE_AGENT);
        }
        __syncthreads();
        if (tid == 0)
            __hip_atomic_store(&progress[b << 5], NS, __ATOMIC_RELEASE,
                               __HIP_MEMORY_SCOPE_AGENT);
        for (int s = tid; s < NS; s += 256) {
            float4 e = hist[s];
            out_pos[(size_t)(b * NS + s) * 3 + 0] = e.y;
            out_pos[(size_t)(b * NS + s) * 3 + 1] = e.z;
            out_pos[(size_t)(b * NS + s) * 3 + 2] = e.w;
            out_batch[b * NS + s] = (float)b;
        }
        return;
    }

    // ======================= consumer: ball + MFMA conv ======================
    const int w = blockIdx.x - NB;  // 0..239
    short* h1s = (short*)smem;                      // 8KB
    short* h2s = (short*)(smem + 8192);             // 8KB
    float* cd2 = (float*)(smem + 16384);            // [4][CAP]
    int*   cix = (int*)(smem + 18432);              // [4][CAP]
    float* dpxA = (float*)(smem + 20480);           // [4][64]
    float* dpyA = (float*)(smem + 21504);
    float* dpzA = (float*)(smem + 22528);
    int*   jA   = (int*)(smem + 23552);             // [4][64]
    float* omax = (float*)(smem + 24576);           // [4][128]
    int*   keepW = (int*)(smem + 26624);            // [4]
    const int lg = lane >> 4;
    const int lr = lane & 15;
    // ---- W fragments (bf16) into registers, once per block ----
    bf16x8 w1f[3][4], w2f[2][4], w3f[2][8];
#pragma unroll
    for (int kt = 0; kt < 3; ++kt)
#pragma unroll
        for (int ct = 0; ct < 4; ++ct) {
            bf16x8 f;
#pragma unroll
            for (int i = 0; i < 8; ++i) {
                int k = 32 * kt + 8 * lg + i;
                float v = (k < 67) ? W1[k * 64 + 16 * ct + lr] : 0.f;
                f[i] = f2bf(v);
            }
            w1f[kt][ct] = f;
        }
#pragma unroll
    for (int kt = 0; kt < 2; ++kt)
#pragma unroll
        for (int ct = 0; ct < 4; ++ct) {
            bf16x8 f;
#pragma unroll
            for (int i = 0; i < 8; ++i) {
                int k = 32 * kt + 8 * lg + i;
                f[i] = f2bf(W2[k * 64 + 16 * ct + lr]);
            }
            w2f[kt][ct] = f;
        }
#pragma unroll
    for (int kt = 0; kt < 2; ++kt)
#pragma unroll
        for (int ct = 0; ct < 8; ++ct) {
            bf16x8 f;
#pragma unroll
            for (int i = 0; i < 8; ++i) {
                int k = 32 * kt + 8 * lg + i;
                f[i] = f2bf(W3[k * 128 + 16 * ct + lr]);
            }
            w3f[kt][ct] = f;
        }
    float b1v[4], b2v[4], b3v[8];
#pragma unroll
    for (int ct = 0; ct < 4; ++ct) {
        b1v[ct] = b1[16 * ct + lr];
        b2v[ct] = b2[16 * ct + lr];
    }
#pragma unroll
    for (int ct = 0; ct < 8; ++ct) b3v[ct] = b3[16 * ct + lr];

    for (int c = w; c < NCHUNK; c += NCONS) {
        const int s = c >> 2;
        const int bq = (c & 3) << 2;
        const int bw = bq + wv;
        while (__hip_atomic_load(&progress[bw << 5], __ATOMIC_ACQUIRE,
                                 __HIP_MEMORY_SCOPE_AGENT) <= s) {
            __builtin_amdgcn_s_sleep(16);
        }
        const size_t ho = ((size_t)(bw * NS + s)) * 3;
        const float ccx = __uint_as_float(__hip_atomic_load(
            (const unsigned*)&histg[ho + 0], __ATOMIC_RELAXED,
            __HIP_MEMORY_SCOPE_AGENT));
        const float ccy = __uint_as_float(__hip_atomic_load(
            (const unsigned*)&histg[ho + 1], __ATOMIC_RELAXED,
            __HIP_MEMORY_SCOPE_AGENT));
        const float ccz = __uint_as_float(__hip_atomic_load(
            (const unsigned*)&histg[ho + 2], __ATOMIC_RELAXED,
            __HIP_MEMORY_SCOPE_AGENT));
        // ---- per-wave ball query ----
        int cnt = 0;
        const float* pcloud = pos + (size_t)bw * NP * 3;
        for (int it = 0; it < 64; ++it) {
            const int j = it * 64 + lane;
            const float* pp = pcloud + (size_t)j * 3;
            float d2 = dist2e(ccx, ccy, ccz, pp[0], pp[1], pp[2]);
            bool in = (d2 <= 0.01f);  // f32(0.1*0.1)
            unsigned long long m = __ballot(in);
            if (in) {
                int slot = cnt + __popcll(m & ((1ull << lane) - 1ull));
                if (slot < CAP) {
                    cd2[wv * CAP + slot] = d2;
                    cix[wv * CAP + slot] = j;
                }
            }
            cnt += __popcll(m);
        }
        if (cnt > CAP) cnt = CAP;
        const int keep = cnt <= KN ? cnt : KN;
        if (lane == 0) keepW[wv] = keep;
        jA[wv * 64 + lane] = 0;
        if (cnt <= KN) {
            if (lane < keep) jA[wv * 64 + lane] = cix[wv * CAP + lane];
        } else {
            // exact K-nearest: rank by (d2, idx) lexicographic (top_k order)
            for (int e = lane; e < cnt; e += 64) {
                float d = cd2[wv * CAP + e];
                int id = cix[wv * CAP + e];
                int rank = 0;
                for (int q = 0; q < cnt; ++q) {
                    float dq = cd2[wv * CAP + q];
                    int iq = cix[wv * CAP + q];
                    rank += (dq < d || (dq == d && iq < id)) ? 1 : 0;
                }
                if (rank < KN) jA[wv * 64 + rank] = id;
            }
        }
        {
            int j = jA[wv * 64 + lane];
            const float* pp = pcloud + (size_t)j * 3;
            bool valid = lane < keep;
            dpxA[wv * 64 + lane] = valid ? (pp[0] - ccx) : 0.f;
            dpyA[wv * 64 + lane] = valid ? (pp[1] - ccy) : 0.f;
            dpzA[wv * 64 + lane] = valid ? (pp[2] - ccz) : 0.f;
        }
        __syncthreads();
        // ---- conv for the 4 centers (R10 MFMA path) ----
        for (int cc = 0; cc < 4; ++cc) {
            const int C = keepW[cc];
            const int cen = (bq + cc) * NS + s;
            const int arow = 16 * wv + lr;
            bf16x8 a0, a1, a2;
            {
                const int jrow = (bq + cc) * NP + jA[cc * 64 + arow];
                const float* xr = x + (size_t)jrow * FIN + 8 * lg;
                float4 v0 = *(const float4*)(xr + 0);
                float4 v1 = *(const float4*)(xr + 4);
                float4 v2 = *(const float4*)(xr + 32);
                float4 v3 = *(const float4*)(xr + 36);
                a0[0] = f2bf(v0.x); a0[1] = f2bf(v0.y); a0[2] = f2bf(v0.z); a0[3] = f2bf(v0.w);
                a0[4] = f2bf(v1.x); a0[5] = f2bf(v1.y); a0[6] = f2bf(v1.z); a0[7] = f2bf(v1.w);
                a1[0] = f2bf(v2.x); a1[1] = f2bf(v2.y); a1[2] = f2bf(v2.z); a1[3] = f2bf(v2.w);
                a1[4] = f2bf(v3.x); a1[5] = f2bf(v3.y); a1[6] = f2bf(v3.z); a1[7] = f2bf(v3.w);
                float d0 = (lg == 0) ? dpxA[cc * 64 + arow] : 0.f;
                float d1 = (lg == 0) ? dpyA[cc * 64 + arow] : 0.f;
                float d2v = (lg == 0) ? dpzA[cc * 64 + arow] : 0.f;
                a2[0] = f2bf(d0); a2[1] = f2bf(d1); a2[2] = f2bf(d2v);
                a2[3] = 0; a2[4] = 0; a2[5] = 0; a2[6] = 0; a2[7] = 0;
            }
            {
                f32x4 acc[4];
#pragma unroll
                for (int ct = 0; ct < 4; ++ct) {
                    acc[ct] = (f32x4){b1v[ct], b1v[ct], b1v[ct], b1v[ct]};
                    acc[ct] = __builtin_amdgcn_mfma_f32_16x16x32_bf16(a0, w1f[0][ct], acc[ct], 0, 0, 0);
                    acc[ct] = __builtin_amdgcn_mfma_f32_16x16x32_bf16(a1, w1f[1][ct], acc[ct], 0, 0, 0);
                    acc[ct] = __builtin_amdgcn_mfma_f32_16x16x32_bf16(a2, w1f[2][ct], acc[ct], 0, 0, 0);
                }
#pragma unroll
                for (int ct = 0; ct < 4; ++ct)
#pragma unroll
                    for (int r = 0; r < 4; ++r) {
                        int rw = 16 * wv + 4 * lg + r;
                        int idx = rw * 64 + 16 * ct + lr;
                        h1s[idx ^ ((rw & 7) << 3)] = f2bf(fmaxf(acc[ct][r], 0.f));
                    }
            }
            bf16x8 ha0 = *(bf16x8*)&h1s[(arow * 64 + 0  + 8 * lg) ^ ((arow & 7) << 3)];
            bf16x8 ha1 = *(bf16x8*)&h1s[(arow * 64 + 32 + 8 * lg) ^ ((arow & 7) << 3)];
            {
                f32x4 acc[4];
#pragma unroll
                for (int ct = 0; ct < 4; ++ct) {
                    acc[ct] = (f32x4){b2v[ct], b2v[ct], b2v[ct], b2v[ct]};
                    acc[ct] = __builtin_amdgcn_mfma_f32_16x16x32_bf16(ha0, w2f[0][ct], acc[ct], 0, 0, 0);
                    acc[ct] = __builtin_amdgcn_mfma_f32_16x16x32_bf16(ha1, w2f[1][ct], acc[ct], 0, 0, 0);
                }
#pragma unroll
                for (int ct = 0; ct < 4; ++ct)
#pragma unroll
                    for (int r = 0; r < 4; ++r) {
                        int rw = 16 * wv + 4 * lg + r;
                        int idx = rw * 64 + 16 * ct + lr;
                        h2s[idx ^ ((rw & 7) << 3)] = f2bf(fmaxf(acc[ct][r], 0.f));
                    }
            }
            bf16x8 hb0 = *(bf16x8*)&h2s[(arow * 64 + 0  + 8 * lg) ^ ((arow & 7) << 3)];
            bf16x8 hb1 = *(bf16x8*)&h2s[(arow * 64 + 32 + 8 * lg) ^ ((arow & 7) << 3)];
            {
                f32x4 acc3[8];
#pragma unroll
                for (int ct = 0; ct < 8; ++ct) {
                    acc3[ct] = (f32x4){b3v[ct], b3v[ct], b3v[ct], b3v[ct]};
                    acc3[ct] = __builtin_amdgcn_mfma_f32_16x16x32_bf16(hb0, w3f[0][ct], acc3[ct], 0, 0, 0);
                    acc3[ct] = __builtin_amdgcn_mfma_f32_16x16x32_bf16(hb1, w3f[1][ct], acc3[ct], 0, 0, 0);
                }
#pragma unroll
                for (int ct = 0; ct < 8; ++ct) {
                    float m = -INFINITY;
#pragma unroll
                    for (int r = 0; r < 4; ++r) {
                        int rg = 16 * wv + 4 * lg + r;
                        float v = fmaxf(acc3[ct][r], 0.f);
                        m = (rg < C && v > m) ? v : m;
                    }
                    m = fmaxf(m, __shfl_xor(m, 16, 64));
                    m = fmaxf(m, __shfl_xor(m, 32, 64));
                    if (lg == 0) omax[wv * 128 + 16 * ct + lr] = m;
                }
            }
            __syncthreads();
            if (tid < 128) {
                float m = fmaxf(fmaxf(omax[0 * 128 + tid], omax[1 * 128 + tid]),
                                fmaxf(omax[2 * 128 + tid], omax[3 * 128 + tid]));
                out_feat[(size_t)cen * 128 + tid] = m;
            }
            __syncthreads();
        }
    }
}

extern "C" void kernel_launch(void* const* d_in, const int* in_sizes, int n_in,
                              void* d_out, int out_size, void* d_ws, size_t ws_size,
                              hipStream_t stream) {
    const float* x   = (const float*)d_in[0];
    const float* pos = (const float*)d_in[1];
    const float* W1  = (const float*)d_in[3];
    const float* b1  = (const float*)d_in[4];
    const float* W2  = (const float*)d_in[5];
    const float* b2  = (const float*)d_in[6];
    const float* W3  = (const float*)d_in[7];
    const float* b3  = (const float*)d_in[8];
    float* out = (float*)d_out;
    char* ws = (char*)d_ws;
    int*   progress = (int*)ws;                    // 16 x 128B padded slots
    float* histg    = (float*)(ws + 4096);         // [16][1024][3] = 192KB
    float* out_feat  = out;                        // [16384][128]
    float* out_pos   = out + (size_t)16384 * 128;  // [16384][3]
    float* out_batch = out + (size_t)16384 * 131;  // [16384]
    hipMemsetAsync(ws, 0, 4096, stream);
    fused_kernel<<<256, 256, 0, stream>>>(pos, x, W1, b1, W2, b2, W3, b3,
                                          out_feat, out_pos, out_batch,
                                          histg, progress);
}